// Round 1
// baseline (804.404 us; speedup 1.0000x reference)
//
#include <hip/hip_runtime.h>
#include <hip/hip_bf16.h>
#include <cstddef>

// ---------------------------------------------------------------------------
// GAT 3-layer network, fp32 reference-faithful implementation.
// Pipeline per layer: GEMM (x@W) -> attn coefs (es,ed) -> per-dst online-
// softmax aggregation over CSR(dst) built once per launch.
// ---------------------------------------------------------------------------

#define TILE 64
#define KT 16

// ---------------- CSR build ----------------

__global__ void count_deg(const int* __restrict__ dst, int* __restrict__ deg, int E) {
    int e = blockIdx.x * blockDim.x + threadIdx.x;
    if (e < E) atomicAdd(&deg[dst[e]], 1);
}

// single-block inclusive scan over deg[0..n), writes row_start[0..n] and
// cursor[i] = exclusive prefix (scatter cursors).
__global__ void scan_kernel(const int* __restrict__ deg, int* __restrict__ row_start,
                            int* __restrict__ cursor, int n) {
    __shared__ int lds[1024];
    __shared__ int carry_s;
    int tid = threadIdx.x;
    if (tid == 0) { carry_s = 0; row_start[0] = 0; }
    __syncthreads();
    for (int base = 0; base < n; base += 1024) {
        int i = base + tid;
        int v = (i < n) ? deg[i] : 0;
        lds[tid] = v;
        __syncthreads();
        for (int off = 1; off < 1024; off <<= 1) {
            int t = (tid >= off) ? lds[tid - off] : 0;
            __syncthreads();
            lds[tid] += t;
            __syncthreads();
        }
        int carry = carry_s;
        if (i < n) {
            int incl = lds[tid] + carry;
            row_start[i + 1] = incl;
            cursor[i] = incl - v;
        }
        __syncthreads();
        if (tid == 1023) carry_s = carry + lds[1023];
        __syncthreads();
    }
}

__global__ void scatter_edges(const int* __restrict__ src, const int* __restrict__ dst,
                              int* __restrict__ cursor, int* __restrict__ srcs, int E) {
    int e = blockIdx.x * blockDim.x + threadIdx.x;
    if (e < E) {
        int p = atomicAdd(&cursor[dst[e]], 1);
        srcs[p] = src[e];
    }
}

// ---------------- GEMM: C[M,Nn] = A[M,K] @ B[K,Nn]  (fp32, 64x64 tile) ------

__global__ __launch_bounds__(256) void gemm_tiled(const float* __restrict__ A,
                                                  const float* __restrict__ B,
                                                  float* __restrict__ C,
                                                  int M, int Nn, int K) {
    __shared__ float As[KT][TILE + 1];   // +1 pad: store bank-conflict fix
    __shared__ float Bs[KT][TILE];
    int tid = threadIdx.x;
    int tx = tid & 15, ty = tid >> 4;
    int row0 = blockIdx.y * TILE, col0 = blockIdx.x * TILE;

    int la_row = tid >> 2;          // 0..63
    int la_q = (tid & 3) * 4;       // 0,4,8,12
    int lb_row = tid >> 4;          // 0..15
    int lb_col = (tid & 15) * 4;    // 0..60

    bool a_ok = (row0 + la_row) < M;
    const float* Aptr = A + (size_t)(row0 + la_row) * K;

    float acc[4][4] = {};
    for (int k0 = 0; k0 < K; k0 += KT) {
        float4 av = a_ok ? *(const float4*)(Aptr + k0 + la_q) : make_float4(0.f, 0.f, 0.f, 0.f);
        float4 bv = *(const float4*)(B + (size_t)(k0 + lb_row) * Nn + col0 + lb_col);
        __syncthreads();
        As[la_q + 0][la_row] = av.x;
        As[la_q + 1][la_row] = av.y;
        As[la_q + 2][la_row] = av.z;
        As[la_q + 3][la_row] = av.w;
        *(float4*)&Bs[lb_row][lb_col] = bv;
        __syncthreads();
#pragma unroll
        for (int kk = 0; kk < KT; ++kk) {
            float a[4], b[4];
#pragma unroll
            for (int i = 0; i < 4; ++i) a[i] = As[kk][ty * 4 + i];
#pragma unroll
            for (int j = 0; j < 4; ++j) b[j] = Bs[kk][tx * 4 + j];
#pragma unroll
            for (int i = 0; i < 4; ++i)
#pragma unroll
                for (int j = 0; j < 4; ++j) acc[i][j] += a[i] * b[j];
        }
    }
#pragma unroll
    for (int i = 0; i < 4; ++i) {
        int row = row0 + ty * 4 + i;
        if (row < M) {
            float4 v = make_float4(acc[i][0], acc[i][1], acc[i][2], acc[i][3]);
            *(float4*)&C[(size_t)row * Nn + col0 + tx * 4] = v;
        }
    }
}

// ---------------- attention coefficients: es/ed [N,H] ----------------------

__global__ void attn_coef(const float* __restrict__ h, const float* __restrict__ a_src,
                          const float* __restrict__ a_dst, float* __restrict__ es,
                          float* __restrict__ ed, int Nn, int Hh, int C) {
    int gw = (blockIdx.x * blockDim.x + threadIdx.x) >> 6;
    int lane = threadIdx.x & 63;
    if (gw >= Nn * Hh) return;
    int n = gw / Hh, hd = gw - n * Hh;
    const float* hp = h + (size_t)n * Hh * C + hd * C;
    const float* ap = a_src + hd * C;
    const float* dp = a_dst + hd * C;
    float ss = 0.f, sd = 0.f;
    for (int c = lane; c < C; c += 64) {
        float hv = hp[c];
        ss += hv * ap[c];
        sd += hv * dp[c];
    }
#pragma unroll
    for (int off = 32; off; off >>= 1) {
        ss += __shfl_down(ss, off);
        sd += __shfl_down(sd, off);
    }
    if (lane == 0) { es[gw] = ss; ed[gw] = sd; }
}

// ---------------- aggregation: online softmax over in-edges ----------------
// concat layers (1,2): block = Hh*C threads, one (head,channel) each.
// fused: + bias + residual, ELU, write next-layer x.

__global__ __launch_bounds__(512) void aggregate_concat(
    const float* __restrict__ h, const float* __restrict__ es, const float* __restrict__ ed,
    const int* __restrict__ row_start, const int* __restrict__ srcs,
    const float* __restrict__ bias, const float* __restrict__ x_res,
    float* __restrict__ x_out, int Hh, int C) {
    int n = blockIdx.x;
    int tid = threadIdx.x;
    int head = tid / C;
    int HC = Hh * C;
    float ed_n = ed[n * Hh + head];
    int beg = row_start[n], end = row_start[n + 1];
    float m = -INFINITY, den = 0.f, acc = 0.f;
    for (int j = beg; j < end; ++j) {
        int s = srcs[j];
        float e = es[s * Hh + head] + ed_n;
        e = (e > 0.f) ? e : 0.2f * e;
        float hv = h[(size_t)s * HC + tid];
        if (e > m) {
            float sc = __expf(m - e);   // exp(-inf)=0 on first edge
            den = den * sc + 1.f;
            acc = acc * sc + hv;
            m = e;
        } else {
            float w = __expf(e - m);
            den += w;
            acc += w * hv;
        }
    }
    float v = acc / (den + 1e-16f) + bias[tid] + x_res[(size_t)n * HC + tid];
    v = (v > 0.f) ? v : expm1f(v);   // ELU
    x_out[(size_t)n * HC + tid] = v;
}

// mean layer (3): 2 heads x 512 ch, mean over heads, + bias + residual.
__global__ __launch_bounds__(1024) void aggregate_mean(
    const float* __restrict__ h, const float* __restrict__ es, const float* __restrict__ ed,
    const int* __restrict__ row_start, const int* __restrict__ srcs,
    const float* __restrict__ bias, const float* __restrict__ x_res,
    float* __restrict__ out, int C) {
    __shared__ float tmp[1024];
    int n = blockIdx.x;
    int tid = threadIdx.x;          // 1024 = 2*512
    int head = tid >> 9;
    float ed_n = ed[n * 2 + head];
    int beg = row_start[n], end = row_start[n + 1];
    float m = -INFINITY, den = 0.f, acc = 0.f;
    for (int j = beg; j < end; ++j) {
        int s = srcs[j];
        float e = es[s * 2 + head] + ed_n;
        e = (e > 0.f) ? e : 0.2f * e;
        float hv = h[(size_t)s * 1024 + tid];
        if (e > m) {
            float sc = __expf(m - e);
            den = den * sc + 1.f;
            acc = acc * sc + hv;
            m = e;
        } else {
            float w = __expf(e - m);
            den += w;
            acc += w * hv;
        }
    }
    tmp[tid] = acc / (den + 1e-16f);
    __syncthreads();
    if (tid < 512) {
        float v = 0.5f * (tmp[tid] + tmp[tid + 512]) + bias[tid] + x_res[(size_t)n * 512 + tid];
        out[(size_t)n * 512 + tid] = v;
    }
}

// ---------------------------------------------------------------------------

extern "C" void kernel_launch(void* const* d_in, const int* in_sizes, int n_in,
                              void* d_out, int out_size, void* d_ws, size_t ws_size,
                              hipStream_t stream) {
    const float* graph = (const float*)d_in[0];
    const int* edge_index = (const int*)d_in[1];
    const float* W1 = (const float*)d_in[2];
    const float* as1 = (const float*)d_in[3];
    const float* ad1 = (const float*)d_in[4];
    const float* b1 = (const float*)d_in[5];
    const float* W2 = (const float*)d_in[6];
    const float* as2 = (const float*)d_in[7];
    const float* ad2 = (const float*)d_in[8];
    const float* b2 = (const float*)d_in[9];
    const float* W3 = (const float*)d_in[10];
    const float* as3 = (const float*)d_in[11];
    const float* ad3 = (const float*)d_in[12];
    const float* b3 = (const float*)d_in[13];

    const int D = 512;
    int N = in_sizes[0] / D;       // 10000
    int E = in_sizes[1] / 2;       // 160000
    const int* src = edge_index;
    const int* dst = edge_index + E;

    // workspace carve (all re-poisoned each launch; everything written before read)
    char* p = (char*)d_ws;
    auto carve = [&](size_t bytes) {
        void* r = (void*)p;
        p += (bytes + 255) & ~(size_t)255;
        return r;
    };
    float* h_buf = (float*)carve((size_t)N * 1024 * 4);  // max H*C = 1024
    float* x1 = (float*)carve((size_t)N * 512 * 4);
    float* x2 = (float*)carve((size_t)N * 512 * 4);
    float* es = (float*)carve((size_t)N * 4 * 4);
    float* ed = (float*)carve((size_t)N * 4 * 4);
    int* deg = (int*)carve((size_t)N * 4);
    int* cur = (int*)carve((size_t)N * 4);
    int* row_start = (int*)carve((size_t)(N + 1) * 4);
    int* srcs = (int*)carve((size_t)E * 4);

    // ---- CSR by dst (shared by all 3 layers) ----
    hipMemsetAsync(deg, 0, (size_t)N * 4, stream);
    count_deg<<<(E + 255) / 256, 256, 0, stream>>>(dst, deg, E);
    scan_kernel<<<1, 1024, 0, stream>>>(deg, row_start, cur, N);
    scatter_edges<<<(E + 255) / 256, 256, 0, stream>>>(src, dst, cur, srcs, E);

    dim3 blk(256);
    // ---- Layer 1: H=4, C=128, concat, ELU + residual ----
    {
        dim3 grid(512 / TILE, (N + TILE - 1) / TILE);
        gemm_tiled<<<grid, blk, 0, stream>>>(graph, W1, h_buf, N, 512, 512);
        int waves = N * 4;
        attn_coef<<<(waves * 64 + 255) / 256, 256, 0, stream>>>(h_buf, as1, ad1, es, ed, N, 4, 128);
        aggregate_concat<<<N, 512, 0, stream>>>(h_buf, es, ed, row_start, srcs, b1, graph, x1, 4, 128);
    }
    // ---- Layer 2 ----
    {
        dim3 grid(512 / TILE, (N + TILE - 1) / TILE);
        gemm_tiled<<<grid, blk, 0, stream>>>(x1, W2, h_buf, N, 512, 512);
        int waves = N * 4;
        attn_coef<<<(waves * 64 + 255) / 256, 256, 0, stream>>>(h_buf, as2, ad2, es, ed, N, 4, 128);
        aggregate_concat<<<N, 512, 0, stream>>>(h_buf, es, ed, row_start, srcs, b2, x1, x2, 4, 128);
    }
    // ---- Layer 3: HF=2, CF=512, mean, residual (no ELU) ----
    {
        dim3 grid(1024 / TILE, (N + TILE - 1) / TILE);
        gemm_tiled<<<grid, blk, 0, stream>>>(x2, W3, h_buf, N, 1024, 512);
        int waves = N * 2;
        attn_coef<<<(waves * 64 + 255) / 256, 256, 0, stream>>>(h_buf, as3, ad3, es, ed, N, 2, 512);
        aggregate_mean<<<N, 1024, 0, stream>>>(h_buf, es, ed, row_start, srcs, b3, x2, (float*)d_out, 512);
    }
}

// Round 2
// 436.043 us; speedup vs baseline: 1.8448x; 1.8448x over previous
//
#include <hip/hip_runtime.h>
#include <hip/hip_bf16.h>
#include <hip/hip_fp16.h>
#include <cstddef>
#include <cstdint>

// ---------------------------------------------------------------------------
// GAT 3-layer network. R2: fp16 MFMA GEMMs + fp16 message gather + two-pass
// (precomputed-alpha) softmax aggregation over CSR(dst).
// ---------------------------------------------------------------------------

typedef _Float16 half8 __attribute__((ext_vector_type(8)));
typedef _Float16 half4v __attribute__((ext_vector_type(4)));
typedef _Float16 half2v __attribute__((ext_vector_type(2)));
typedef float floatx4 __attribute__((ext_vector_type(4)));

#define AS1(p) ((const __attribute__((address_space(1))) void*)(p))
#define AS3(p) ((__attribute__((address_space(3))) void*)(p))

// ---------------- CSR build ----------------

__global__ void count_deg(const int* __restrict__ dst, int* __restrict__ deg, int E) {
    int e = blockIdx.x * blockDim.x + threadIdx.x;
    if (e < E) atomicAdd(&deg[dst[e]], 1);
}

__global__ void scan_kernel(const int* __restrict__ deg, int* __restrict__ row_start,
                            int* __restrict__ cursor, int n) {
    __shared__ int lds[1024];
    __shared__ int carry_s;
    int tid = threadIdx.x;
    if (tid == 0) { carry_s = 0; row_start[0] = 0; }
    __syncthreads();
    for (int base = 0; base < n; base += 1024) {
        int i = base + tid;
        int v = (i < n) ? deg[i] : 0;
        lds[tid] = v;
        __syncthreads();
        for (int off = 1; off < 1024; off <<= 1) {
            int t = (tid >= off) ? lds[tid - off] : 0;
            __syncthreads();
            lds[tid] += t;
            __syncthreads();
        }
        int carry = carry_s;
        if (i < n) {
            int incl = lds[tid] + carry;
            row_start[i + 1] = incl;
            cursor[i] = incl - v;
        }
        __syncthreads();
        if (tid == 1023) carry_s = carry + lds[1023];
        __syncthreads();
    }
}

__global__ void scatter_edges(const int* __restrict__ src, const int* __restrict__ dst,
                              int* __restrict__ cursor, int* __restrict__ srcs, int E) {
    int e = blockIdx.x * blockDim.x + threadIdx.x;
    if (e < E) {
        int p = atomicAdd(&cursor[dst[e]], 1);
        srcs[p] = src[e];
    }
}

// ---------------- casts ----------------

__global__ void cast_f16(const float* __restrict__ in, _Float16* __restrict__ out, int n4) {
    int i = blockIdx.x * blockDim.x + threadIdx.x;
    if (i < n4) {
        float4 v = ((const float4*)in)[i];
        half4v o = {(_Float16)v.x, (_Float16)v.y, (_Float16)v.z, (_Float16)v.w};
        ((half4v*)out)[i] = o;
    }
}

// fp32 [K][Nn] -> f16 [Nn][K] (transpose for GEMM B staging)
__global__ void transpose_cast(const float* __restrict__ in, _Float16* __restrict__ out,
                               int K, int Nn) {
    __shared__ float t[32][33];
    int k0 = blockIdx.y * 32, n0 = blockIdx.x * 32;
    int tx = threadIdx.x, ty = threadIdx.y;   // 32 x 8
    for (int i = ty; i < 32; i += 8)
        t[i][tx] = in[(size_t)(k0 + i) * Nn + n0 + tx];
    __syncthreads();
    for (int i = ty; i < 32; i += 8)
        out[(size_t)(n0 + i) * K + k0 + tx] = (_Float16)t[tx][i];
}

// ---------------- MFMA GEMM: C[M,Nn] = A[M,K] @ Bt[Nn,K]^T, f16 in/out -----
// 128x128 tile, BK=64, 4 waves (2x2 of 64x64), 16x16x32 f16 MFMA.

#define BM 128
#define BN 128
#define BK 64

__global__ __launch_bounds__(256) void gemm_f16(const _Float16* __restrict__ A,
                                                const _Float16* __restrict__ Bt,
                                                _Float16* __restrict__ C,
                                                int M, int Nn, int K) {
    __shared__ _Float16 As[BM * BK];   // [m][k], 128B rows
    __shared__ _Float16 Bs[BN * BK];   // [n][k]
    int tid = threadIdx.x;
    int lane = tid & 63, wave = tid >> 6;
    int wm = (wave & 1) * 64, wn = (wave >> 1) * 64;
    int m0 = blockIdx.y * BM, n0 = blockIdx.x * BN;
    int l15 = lane & 15, quad = lane >> 4;
    int trow = tid >> 3, tcol = tid & 7;   // staging: row=i*32+trow, 16B chunk tcol

    floatx4 acc[4][4];
#pragma unroll
    for (int i = 0; i < 4; ++i)
#pragma unroll
        for (int j = 0; j < 4; ++j) acc[i][j] = (floatx4){0.f, 0.f, 0.f, 0.f};

    for (int k0 = 0; k0 < K; k0 += BK) {
        __syncthreads();   // protect previous iter's LDS reads
#pragma unroll
        for (int i = 0; i < 4; ++i) {
            int r = i * 32 + trow;
            int gr = m0 + r; if (gr >= M) gr = M - 1;
            const _Float16* gp = A + (size_t)gr * K + k0 + tcol * 8;
            _Float16* lp = As + (size_t)(i * 256 + tid) * 8;
            __builtin_amdgcn_global_load_lds(AS1(gp), AS3(lp), 16, 0, 0);
        }
#pragma unroll
        for (int i = 0; i < 4; ++i) {
            int r = i * 32 + trow;
            const _Float16* gp = Bt + (size_t)(n0 + r) * K + k0 + tcol * 8;
            _Float16* lp = Bs + (size_t)(i * 256 + tid) * 8;
            __builtin_amdgcn_global_load_lds(AS1(gp), AS3(lp), 16, 0, 0);
        }
        __syncthreads();   // drains vmcnt before barrier
#pragma unroll
        for (int ks = 0; ks < BK; ks += 32) {
            half8 af[4], bfr[4];
#pragma unroll
            for (int i = 0; i < 4; ++i)
                af[i] = *(const half8*)&As[(wm + i * 16 + l15) * BK + ks + quad * 8];
#pragma unroll
            for (int j = 0; j < 4; ++j)
                bfr[j] = *(const half8*)&Bs[(wn + j * 16 + l15) * BK + ks + quad * 8];
#pragma unroll
            for (int i = 0; i < 4; ++i)
#pragma unroll
                for (int j = 0; j < 4; ++j)
                    acc[i][j] = __builtin_amdgcn_mfma_f32_16x16x32_f16(af[i], bfr[j], acc[i][j], 0, 0, 0);
        }
    }
    // D layout: col = lane&15, row = quad*4 + r
#pragma unroll
    for (int i = 0; i < 4; ++i)
#pragma unroll
        for (int j = 0; j < 4; ++j) {
            int col = n0 + wn + j * 16 + l15;
#pragma unroll
            for (int r = 0; r < 4; ++r) {
                int row = m0 + wm + i * 16 + quad * 4 + r;
                if (row < M) C[(size_t)row * Nn + col] = (_Float16)acc[i][j][r];
            }
        }
}

// ---------------- attention coefficients: es/ed [N*H] ----------------------

__global__ void attn_coef(const _Float16* __restrict__ h, const float* __restrict__ a_src,
                          const float* __restrict__ a_dst, float* __restrict__ es,
                          float* __restrict__ ed, int NH, int Hh, int C) {
    int gw = (blockIdx.x * blockDim.x + threadIdx.x) >> 6;
    int lane = threadIdx.x & 63;
    if (gw >= NH) return;
    int hd = gw % Hh;
    const _Float16* hp = h + (size_t)gw * C;
    const float* ap = a_src + hd * C;
    const float* dp = a_dst + hd * C;
    float ss = 0.f, sd = 0.f;
    for (int c = lane; c < C; c += 64) {
        float hv = (float)hp[c];
        ss += hv * ap[c];
        sd += hv * dp[c];
    }
#pragma unroll
    for (int off = 32; off; off >>= 1) {
        ss += __shfl_down(ss, off);
        sd += __shfl_down(sd, off);
    }
    if (lane == 0) { es[gw] = ss; ed[gw] = sd; }
}

// ---------------- pass 1: normalized alpha per (edge, head), [H][E] --------

__global__ void attn_alpha(const float* __restrict__ es, const float* __restrict__ ed,
                           const int* __restrict__ row_start, const int* __restrict__ srcs,
                           float* __restrict__ alpha, int Nn, int Hh, int E) {
    int gw = (blockIdx.x * blockDim.x + threadIdx.x) >> 6;
    int lane = threadIdx.x & 63;
    if (gw >= Nn * Hh) return;
    int n = gw / Hh, hd = gw - n * Hh;
    float edn = ed[n * Hh + hd];
    int beg = row_start[n], end = row_start[n + 1];
    float m = -INFINITY;
    for (int j = beg + lane; j < end; j += 64) {
        float e = es[srcs[j] * Hh + hd] + edn;
        e = (e > 0.f) ? e : 0.2f * e;
        m = fmaxf(m, e);
    }
#pragma unroll
    for (int off = 32; off; off >>= 1) m = fmaxf(m, __shfl_xor(m, off));
    float den = 0.f;
    for (int j = beg + lane; j < end; j += 64) {
        float e = es[srcs[j] * Hh + hd] + edn;
        e = (e > 0.f) ? e : 0.2f * e;
        den += __expf(e - m);
    }
#pragma unroll
    for (int off = 32; off; off >>= 1) den += __shfl_xor(den, off);
    float inv = 1.f / (den + 1e-16f);
    for (int j = beg + lane; j < end; j += 64) {
        float e = es[srcs[j] * Hh + hd] + edn;
        e = (e > 0.f) ? e : 0.2f * e;
        alpha[(size_t)hd * E + j] = __expf(e - m) * inv;
    }
}

// ---------------- pass 2: weighted gather-accumulate -----------------------
// concat layers: 256 threads/node, thread = 2 channels of 512; head = tid>>6.

__global__ __launch_bounds__(256) void aggregate2_concat(
    const _Float16* __restrict__ h, const float* __restrict__ alpha,
    const int* __restrict__ row_start, const int* __restrict__ srcs,
    const float* __restrict__ bias, const float* __restrict__ x_res,
    float* __restrict__ x_out, _Float16* __restrict__ x_out_h, int E) {
    int n = blockIdx.x;
    int tid = threadIdx.x;
    int head = tid >> 6;
    const float* al = alpha + (size_t)head * E;
    int beg = row_start[n], end = row_start[n + 1];
    float a0 = 0.f, a1 = 0.f;
    for (int j = beg; j < end; ++j) {
        int s = srcs[j];
        float w = al[j];
        half2v hv = *(const half2v*)&h[(size_t)s * 512 + tid * 2];
        a0 += w * (float)hv[0];
        a1 += w * (float)hv[1];
    }
    int c0 = tid * 2;
    float v0 = a0 + bias[c0] + x_res[(size_t)n * 512 + c0];
    float v1 = a1 + bias[c0 + 1] + x_res[(size_t)n * 512 + c0 + 1];
    v0 = (v0 > 0.f) ? v0 : expm1f(v0);
    v1 = (v1 > 0.f) ? v1 : expm1f(v1);
    x_out[(size_t)n * 512 + c0] = v0;
    x_out[(size_t)n * 512 + c0 + 1] = v1;
    x_out_h[(size_t)n * 512 + c0] = (_Float16)v0;
    x_out_h[(size_t)n * 512 + c0 + 1] = (_Float16)v1;
}

// mean layer: 512 threads/node, thread = 2 channels of 1024; head = tid>>8.
__global__ __launch_bounds__(512) void aggregate2_mean(
    const _Float16* __restrict__ h, const float* __restrict__ alpha,
    const int* __restrict__ row_start, const int* __restrict__ srcs,
    const float* __restrict__ bias, const float* __restrict__ x_res,
    float* __restrict__ out, int E) {
    __shared__ float tmp[1024];
    int n = blockIdx.x, tid = threadIdx.x;
    int head = tid >> 8;
    const float* al = alpha + (size_t)head * E;
    int beg = row_start[n], end = row_start[n + 1];
    float a0 = 0.f, a1 = 0.f;
    for (int j = beg; j < end; ++j) {
        int s = srcs[j];
        float w = al[j];
        half2v hv = *(const half2v*)&h[(size_t)s * 1024 + tid * 2];
        a0 += w * (float)hv[0];
        a1 += w * (float)hv[1];
    }
    tmp[tid * 2] = a0;
    tmp[tid * 2 + 1] = a1;
    __syncthreads();
    if (tid < 256) {
        int c0 = tid * 2;
        float v0 = 0.5f * (tmp[c0] + tmp[c0 + 512]) + bias[c0] + x_res[(size_t)n * 512 + c0];
        float v1 = 0.5f * (tmp[c0 + 1] + tmp[c0 + 513]) + bias[c0 + 1] + x_res[(size_t)n * 512 + c0 + 1];
        out[(size_t)n * 512 + c0] = v0;
        out[(size_t)n * 512 + c0 + 1] = v1;
    }
}

// ---------------------------------------------------------------------------

extern "C" void kernel_launch(void* const* d_in, const int* in_sizes, int n_in,
                              void* d_out, int out_size, void* d_ws, size_t ws_size,
                              hipStream_t stream) {
    const float* graph = (const float*)d_in[0];
    const int* edge_index = (const int*)d_in[1];
    const float* W1 = (const float*)d_in[2];
    const float* as1 = (const float*)d_in[3];
    const float* ad1 = (const float*)d_in[4];
    const float* b1 = (const float*)d_in[5];
    const float* W2 = (const float*)d_in[6];
    const float* as2 = (const float*)d_in[7];
    const float* ad2 = (const float*)d_in[8];
    const float* b2 = (const float*)d_in[9];
    const float* W3 = (const float*)d_in[10];
    const float* as3 = (const float*)d_in[11];
    const float* ad3 = (const float*)d_in[12];
    const float* b3 = (const float*)d_in[13];

    const int D = 512;
    int N = in_sizes[0] / D;       // 10000
    int E = in_sizes[1] / 2;       // 160000
    const int* src = edge_index;
    const int* dst = edge_index + E;

    char* p = (char*)d_ws;
    auto carve = [&](size_t bytes) {
        void* r = (void*)p;
        p += (bytes + 255) & ~(size_t)255;
        return r;
    };
    _Float16* Ah  = (_Float16*)carve((size_t)N * 512 * 2);   // graph_h / x1h / x2h (reused)
    _Float16* Wt  = (_Float16*)carve((size_t)1024 * 512 * 2);// per-layer B^T (reused)
    _Float16* h_h = (_Float16*)carve((size_t)N * 1024 * 2);
    float* x1     = (float*)carve((size_t)N * 512 * 4);
    float* x2     = (float*)carve((size_t)N * 512 * 4);
    float* es     = (float*)carve((size_t)N * 4 * 4);
    float* ed     = (float*)carve((size_t)N * 4 * 4);
    float* alpha  = (float*)carve((size_t)4 * E * 4);
    int* deg      = (int*)carve((size_t)N * 4);
    int* cur      = (int*)carve((size_t)N * 4);
    int* row_st   = (int*)carve((size_t)(N + 1) * 4);
    int* srcs     = (int*)carve((size_t)E * 4);

    // ---- CSR by dst (shared by all layers) ----
    hipMemsetAsync(deg, 0, (size_t)N * 4, stream);
    count_deg<<<(E + 255) / 256, 256, 0, stream>>>(dst, deg, E);
    scan_kernel<<<1, 1024, 0, stream>>>(deg, row_st, cur, N);
    scatter_edges<<<(E + 255) / 256, 256, 0, stream>>>(src, dst, cur, srcs, E);

    // ---- graph -> f16 ----
    cast_f16<<<(N * 512 / 4 + 255) / 256, 256, 0, stream>>>(graph, Ah, N * 512 / 4);

    dim3 tblk(32, 8);
    // ---- Layer 1: H=4, C=128, concat, ELU + residual ----
    transpose_cast<<<dim3(512 / 32, 512 / 32), tblk, 0, stream>>>(W1, Wt, 512, 512);
    gemm_f16<<<dim3(512 / BN, (N + BM - 1) / BM), 256, 0, stream>>>(Ah, Wt, h_h, N, 512, 512);
    attn_coef<<<(N * 4 + 3) / 4, 256, 0, stream>>>(h_h, as1, ad1, es, ed, N * 4, 4, 128);
    attn_alpha<<<(N * 4 + 3) / 4, 256, 0, stream>>>(es, ed, row_st, srcs, alpha, N, 4, E);
    aggregate2_concat<<<N, 256, 0, stream>>>(h_h, alpha, row_st, srcs, b1, graph, x1, Ah, E);

    // ---- Layer 2 ----
    transpose_cast<<<dim3(512 / 32, 512 / 32), tblk, 0, stream>>>(W2, Wt, 512, 512);
    gemm_f16<<<dim3(512 / BN, (N + BM - 1) / BM), 256, 0, stream>>>(Ah, Wt, h_h, N, 512, 512);
    attn_coef<<<(N * 4 + 3) / 4, 256, 0, stream>>>(h_h, as2, ad2, es, ed, N * 4, 4, 128);
    attn_alpha<<<(N * 4 + 3) / 4, 256, 0, stream>>>(es, ed, row_st, srcs, alpha, N, 4, E);
    aggregate2_concat<<<N, 256, 0, stream>>>(h_h, alpha, row_st, srcs, b2, x1, x2, Ah, E);

    // ---- Layer 3: HF=2, CF=512, mean, residual (no ELU) ----
    transpose_cast<<<dim3(1024 / 32, 512 / 32), tblk, 0, stream>>>(W3, Wt, 512, 1024);
    gemm_f16<<<dim3(1024 / BN, (N + BM - 1) / BM), 256, 0, stream>>>(Ah, Wt, h_h, N, 1024, 512);
    attn_coef<<<(N * 2 + 3) / 4, 256, 0, stream>>>(h_h, as3, ad3, es, ed, N * 2, 2, 512);
    attn_alpha<<<(N * 2 + 3) / 4, 256, 0, stream>>>(es, ed, row_st, srcs, alpha, N, 2, E);
    aggregate2_mean<<<N, 512, 0, stream>>>(h_h, alpha, row_st, srcs, b3, x2, (float*)d_out, E);
}

// Round 3
// 378.279 us; speedup vs baseline: 2.1265x; 1.1527x over previous
//
#include <hip/hip_runtime.h>
#include <hip/hip_bf16.h>
#include <hip/hip_fp16.h>
#include <cstddef>
#include <cstdint>

// ---------------------------------------------------------------------------
// GAT 3-layer network. R3: aggregation rebuilt for MLP — 4 edge-slots in
// flight per block, half8 (16B) gathers, LDS cross-slot reduce.
// ---------------------------------------------------------------------------

typedef _Float16 half8 __attribute__((ext_vector_type(8)));
typedef _Float16 half4v __attribute__((ext_vector_type(4)));
typedef float floatx4 __attribute__((ext_vector_type(4)));

#define AS1(p) ((const __attribute__((address_space(1))) void*)(p))
#define AS3(p) ((__attribute__((address_space(3))) void*)(p))

// ---------------- CSR build ----------------

__global__ void count_deg(const int* __restrict__ dst, int* __restrict__ deg, int E) {
    int e = blockIdx.x * blockDim.x + threadIdx.x;
    if (e < E) atomicAdd(&deg[dst[e]], 1);
}

// single-block scan, shuffle-based (4 barriers per 1024-chunk)
__global__ void scan_kernel(const int* __restrict__ deg, int* __restrict__ row_start,
                            int* __restrict__ cursor, int n) {
    __shared__ int wsum[16];
    __shared__ int carry_s;
    int tid = threadIdx.x;              // 1024
    int wave = tid >> 6, lane = tid & 63;
    if (tid == 0) { carry_s = 0; row_start[0] = 0; }
    __syncthreads();
    for (int base = 0; base < n; base += 1024) {
        int i = base + tid;
        int v = (i < n) ? deg[i] : 0;
        int x = v;
#pragma unroll
        for (int off = 1; off < 64; off <<= 1) {
            int t = __shfl_up(x, off);
            if (lane >= off) x += t;
        }
        if (lane == 63) wsum[wave] = x;
        __syncthreads();
        if (wave == 0 && lane < 16) {
            int w = wsum[lane];
#pragma unroll
            for (int off = 1; off < 16; off <<= 1) {
                int t = __shfl_up(w, off);
                if (lane >= off) w += t;
            }
            wsum[lane] = w;
        }
        __syncthreads();
        int carry = carry_s;
        int incl = x + (wave ? wsum[wave - 1] : 0) + carry;
        if (i < n) { row_start[i + 1] = incl; cursor[i] = incl - v; }
        __syncthreads();
        if (tid == 1023) carry_s = incl;
        __syncthreads();
    }
}

__global__ void scatter_edges(const int* __restrict__ src, const int* __restrict__ dst,
                              int* __restrict__ cursor, int* __restrict__ srcs, int E) {
    int e = blockIdx.x * blockDim.x + threadIdx.x;
    if (e < E) {
        int p = atomicAdd(&cursor[dst[e]], 1);
        srcs[p] = src[e];
    }
}

// ---------------- casts ----------------

__global__ void cast_f16(const float* __restrict__ in, _Float16* __restrict__ out, int n4) {
    int i = blockIdx.x * blockDim.x + threadIdx.x;
    if (i < n4) {
        float4 v = ((const float4*)in)[i];
        half4v o = {(_Float16)v.x, (_Float16)v.y, (_Float16)v.z, (_Float16)v.w};
        ((half4v*)out)[i] = o;
    }
}

// fp32 [K][Nn] -> f16 [Nn][K]
__global__ void transpose_cast(const float* __restrict__ in, _Float16* __restrict__ out,
                               int K, int Nn) {
    __shared__ float t[32][33];
    int k0 = blockIdx.y * 32, n0 = blockIdx.x * 32;
    int tx = threadIdx.x, ty = threadIdx.y;   // 32 x 8
    for (int i = ty; i < 32; i += 8)
        t[i][tx] = in[(size_t)(k0 + i) * Nn + n0 + tx];
    __syncthreads();
    for (int i = ty; i < 32; i += 8)
        out[(size_t)(n0 + i) * K + k0 + tx] = (_Float16)t[tx][i];
}

// ---------------- MFMA GEMM: C[M,Nn] = A[M,K] @ Bt[Nn,K]^T, f16 in/out -----

#define BM 128
#define BN 128
#define BK 64

__global__ __launch_bounds__(256) void gemm_f16(const _Float16* __restrict__ A,
                                                const _Float16* __restrict__ Bt,
                                                _Float16* __restrict__ C,
                                                int M, int Nn, int K) {
    __shared__ _Float16 As[BM * BK];
    __shared__ _Float16 Bs[BN * BK];
    int tid = threadIdx.x;
    int lane = tid & 63, wave = tid >> 6;
    int wm = (wave & 1) * 64, wn = (wave >> 1) * 64;
    int m0 = blockIdx.y * BM, n0 = blockIdx.x * BN;
    int l15 = lane & 15, quad = lane >> 4;
    int trow = tid >> 3, tcol = tid & 7;

    floatx4 acc[4][4];
#pragma unroll
    for (int i = 0; i < 4; ++i)
#pragma unroll
        for (int j = 0; j < 4; ++j) acc[i][j] = (floatx4){0.f, 0.f, 0.f, 0.f};

    for (int k0 = 0; k0 < K; k0 += BK) {
        __syncthreads();
#pragma unroll
        for (int i = 0; i < 4; ++i) {
            int r = i * 32 + trow;
            int gr = m0 + r; if (gr >= M) gr = M - 1;
            const _Float16* gp = A + (size_t)gr * K + k0 + tcol * 8;
            _Float16* lp = As + (size_t)(i * 256 + tid) * 8;
            __builtin_amdgcn_global_load_lds(AS1(gp), AS3(lp), 16, 0, 0);
        }
#pragma unroll
        for (int i = 0; i < 4; ++i) {
            int r = i * 32 + trow;
            const _Float16* gp = Bt + (size_t)(n0 + r) * K + k0 + tcol * 8;
            _Float16* lp = Bs + (size_t)(i * 256 + tid) * 8;
            __builtin_amdgcn_global_load_lds(AS1(gp), AS3(lp), 16, 0, 0);
        }
        __syncthreads();
#pragma unroll
        for (int ks = 0; ks < BK; ks += 32) {
            half8 af[4], bfr[4];
#pragma unroll
            for (int i = 0; i < 4; ++i)
                af[i] = *(const half8*)&As[(wm + i * 16 + l15) * BK + ks + quad * 8];
#pragma unroll
            for (int j = 0; j < 4; ++j)
                bfr[j] = *(const half8*)&Bs[(wn + j * 16 + l15) * BK + ks + quad * 8];
#pragma unroll
            for (int i = 0; i < 4; ++i)
#pragma unroll
                for (int j = 0; j < 4; ++j)
                    acc[i][j] = __builtin_amdgcn_mfma_f32_16x16x32_f16(af[i], bfr[j], acc[i][j], 0, 0, 0);
        }
    }
#pragma unroll
    for (int i = 0; i < 4; ++i)
#pragma unroll
        for (int j = 0; j < 4; ++j) {
            int col = n0 + wn + j * 16 + l15;
#pragma unroll
            for (int r = 0; r < 4; ++r) {
                int row = m0 + wm + i * 16 + quad * 4 + r;
                if (row < M) C[(size_t)row * Nn + col] = (_Float16)acc[i][j][r];
            }
        }
}

// ---------------- attention coefficients: es/ed [N*H] ----------------------

__global__ void attn_coef(const _Float16* __restrict__ h, const float* __restrict__ a_src,
                          const float* __restrict__ a_dst, float* __restrict__ es,
                          float* __restrict__ ed, int NH, int Hh, int C) {
    int gw = (blockIdx.x * blockDim.x + threadIdx.x) >> 6;
    int lane = threadIdx.x & 63;
    if (gw >= NH) return;
    int hd = gw % Hh;
    const _Float16* hp = h + (size_t)gw * C;
    const float* ap = a_src + hd * C;
    const float* dp = a_dst + hd * C;
    float ss = 0.f, sd = 0.f;
    for (int c = lane; c < C; c += 64) {
        float hv = (float)hp[c];
        ss += hv * ap[c];
        sd += hv * dp[c];
    }
#pragma unroll
    for (int off = 32; off; off >>= 1) {
        ss += __shfl_down(ss, off);
        sd += __shfl_down(sd, off);
    }
    if (lane == 0) { es[gw] = ss; ed[gw] = sd; }
}

// ---------------- pass 1: normalized alpha per (edge, head), [H][E] --------

__global__ void attn_alpha(const float* __restrict__ es, const float* __restrict__ ed,
                           const int* __restrict__ row_start, const int* __restrict__ srcs,
                           float* __restrict__ alpha, int Nn, int Hh, int E) {
    int gw = (blockIdx.x * blockDim.x + threadIdx.x) >> 6;
    int lane = threadIdx.x & 63;
    if (gw >= Nn * Hh) return;
    int n = gw / Hh, hd = gw - n * Hh;
    float edn = ed[n * Hh + hd];
    int beg = row_start[n], end = row_start[n + 1];
    float m = -INFINITY;
    for (int j = beg + lane; j < end; j += 64) {
        float e = es[srcs[j] * Hh + hd] + edn;
        e = (e > 0.f) ? e : 0.2f * e;
        m = fmaxf(m, e);
    }
#pragma unroll
    for (int off = 32; off; off >>= 1) m = fmaxf(m, __shfl_xor(m, off));
    float den = 0.f;
    for (int j = beg + lane; j < end; j += 64) {
        float e = es[srcs[j] * Hh + hd] + edn;
        e = (e > 0.f) ? e : 0.2f * e;
        den += __expf(e - m);
    }
#pragma unroll
    for (int off = 32; off; off >>= 1) den += __shfl_xor(den, off);
    float inv = 1.f / (den + 1e-16f);
    for (int j = beg + lane; j < end; j += 64) {
        float e = es[srcs[j] * Hh + hd] + edn;
        e = (e > 0.f) ? e : 0.2f * e;
        alpha[(size_t)hd * E + j] = __expf(e - m) * inv;
    }
}

// ---------------- pass 2: weighted gather-accumulate -----------------------
// concat layers: 256 thr = 4 slots x 64 lanes; lane covers 8 ch (half8 load).

__global__ __launch_bounds__(256) void aggregate3_concat(
    const _Float16* __restrict__ h, const float* __restrict__ alpha,
    const int* __restrict__ row_start, const int* __restrict__ srcs,
    const float* __restrict__ bias, const float* __restrict__ x_res,
    float* __restrict__ x_out, _Float16* __restrict__ x_out_h, int E) {
    __shared__ float red[4][512];
    int n = blockIdx.x;
    int tid = threadIdx.x;
    int slot = tid >> 6, lane = tid & 63;
    int head = lane >> 4;                 // C=128 -> 16 lanes per head
    int c0 = lane * 8;
    const float* al = alpha + (size_t)head * E;
    int beg = row_start[n], end = row_start[n + 1];
    float acc[8] = {};
    for (int j = beg + slot; j < end; j += 4) {
        int s = srcs[j];                  // wave-uniform scalar load
        float w = al[j];                  // wave-uniform scalar load
        half8 hv = *(const half8*)&h[(size_t)s * 512 + c0];
#pragma unroll
        for (int k = 0; k < 8; ++k) acc[k] += w * (float)hv[k];
    }
#pragma unroll
    for (int k = 0; k < 8; ++k) red[slot][c0 + k] = acc[k];
    __syncthreads();
    int c = tid * 2;
    size_t base = (size_t)n * 512 + c;
    float v0 = red[0][c] + red[1][c] + red[2][c] + red[3][c] + bias[c] + x_res[base];
    float v1 = red[0][c + 1] + red[1][c + 1] + red[2][c + 1] + red[3][c + 1]
               + bias[c + 1] + x_res[base + 1];
    v0 = (v0 > 0.f) ? v0 : expm1f(v0);
    v1 = (v1 > 0.f) ? v1 : expm1f(v1);
    x_out[base] = v0;
    x_out[base + 1] = v1;
    x_out_h[base] = (_Float16)v0;
    x_out_h[base + 1] = (_Float16)v1;
}

// mean layer: 512 thr = 4 slots x 128 lanes; lane covers 8 of 1024 ch.
__global__ __launch_bounds__(512) void aggregate3_mean(
    const _Float16* __restrict__ h, const float* __restrict__ alpha,
    const int* __restrict__ row_start, const int* __restrict__ srcs,
    const float* __restrict__ bias, const float* __restrict__ x_res,
    float* __restrict__ out, int E) {
    __shared__ float red[4][1024];
    int n = blockIdx.x, tid = threadIdx.x;
    int slot = tid >> 7, l = tid & 127;
    int head = l >> 6;                    // CF=512 -> 64 lanes per head
    int c0 = l * 8;
    const float* al = alpha + (size_t)head * E;
    int beg = row_start[n], end = row_start[n + 1];
    float acc[8] = {};
    for (int j = beg + slot; j < end; j += 4) {
        int s = srcs[j];
        float w = al[j];
        half8 hv = *(const half8*)&h[(size_t)s * 1024 + c0];
#pragma unroll
        for (int k = 0; k < 8; ++k) acc[k] += w * (float)hv[k];
    }
#pragma unroll
    for (int k = 0; k < 8; ++k) red[slot][c0 + k] = acc[k];
    __syncthreads();
    if (tid < 256) {
        int c = tid * 2;
        size_t base = (size_t)n * 512 + c;
        float s0 = red[0][c] + red[1][c] + red[2][c] + red[3][c];
        float s0h = red[0][c + 512] + red[1][c + 512] + red[2][c + 512] + red[3][c + 512];
        float s1 = red[0][c + 1] + red[1][c + 1] + red[2][c + 1] + red[3][c + 1];
        float s1h = red[0][c + 513] + red[1][c + 513] + red[2][c + 513] + red[3][c + 513];
        out[base] = 0.5f * (s0 + s0h) + bias[c] + x_res[base];
        out[base + 1] = 0.5f * (s1 + s1h) + bias[c + 1] + x_res[base + 1];
    }
}

// ---------------------------------------------------------------------------

extern "C" void kernel_launch(void* const* d_in, const int* in_sizes, int n_in,
                              void* d_out, int out_size, void* d_ws, size_t ws_size,
                              hipStream_t stream) {
    const float* graph = (const float*)d_in[0];
    const int* edge_index = (const int*)d_in[1];
    const float* W1 = (const float*)d_in[2];
    const float* as1 = (const float*)d_in[3];
    const float* ad1 = (const float*)d_in[4];
    const float* b1 = (const float*)d_in[5];
    const float* W2 = (const float*)d_in[6];
    const float* as2 = (const float*)d_in[7];
    const float* ad2 = (const float*)d_in[8];
    const float* b2 = (const float*)d_in[9];
    const float* W3 = (const float*)d_in[10];
    const float* as3 = (const float*)d_in[11];
    const float* ad3 = (const float*)d_in[12];
    const float* b3 = (const float*)d_in[13];

    const int D = 512;
    int N = in_sizes[0] / D;       // 10000
    int E = in_sizes[1] / 2;       // 160000
    const int* src = edge_index;
    const int* dst = edge_index + E;

    char* p = (char*)d_ws;
    auto carve = [&](size_t bytes) {
        void* r = (void*)p;
        p += (bytes + 255) & ~(size_t)255;
        return r;
    };
    _Float16* Ah  = (_Float16*)carve((size_t)N * 512 * 2);
    _Float16* Wt  = (_Float16*)carve((size_t)1024 * 512 * 2);
    _Float16* h_h = (_Float16*)carve((size_t)N * 1024 * 2);
    float* x1     = (float*)carve((size_t)N * 512 * 4);
    float* x2     = (float*)carve((size_t)N * 512 * 4);
    float* es     = (float*)carve((size_t)N * 4 * 4);
    float* ed     = (float*)carve((size_t)N * 4 * 4);
    float* alpha  = (float*)carve((size_t)4 * E * 4);
    int* deg      = (int*)carve((size_t)N * 4);
    int* cur      = (int*)carve((size_t)N * 4);
    int* row_st   = (int*)carve((size_t)(N + 1) * 4);
    int* srcs     = (int*)carve((size_t)E * 4);

    // ---- CSR by dst (shared by all layers) ----
    hipMemsetAsync(deg, 0, (size_t)N * 4, stream);
    count_deg<<<(E + 255) / 256, 256, 0, stream>>>(dst, deg, E);
    scan_kernel<<<1, 1024, 0, stream>>>(deg, row_st, cur, N);
    scatter_edges<<<(E + 255) / 256, 256, 0, stream>>>(src, dst, cur, srcs, E);

    // ---- graph -> f16 ----
    cast_f16<<<(N * 512 / 4 + 255) / 256, 256, 0, stream>>>(graph, Ah, N * 512 / 4);

    dim3 tblk(32, 8);
    // ---- Layer 1: H=4, C=128, concat, ELU + residual ----
    transpose_cast<<<dim3(512 / 32, 512 / 32), tblk, 0, stream>>>(W1, Wt, 512, 512);
    gemm_f16<<<dim3(512 / BN, (N + BM - 1) / BM), 256, 0, stream>>>(Ah, Wt, h_h, N, 512, 512);
    attn_coef<<<(N * 4 + 3) / 4, 256, 0, stream>>>(h_h, as1, ad1, es, ed, N * 4, 4, 128);
    attn_alpha<<<(N * 4 + 3) / 4, 256, 0, stream>>>(es, ed, row_st, srcs, alpha, N, 4, E);
    aggregate3_concat<<<N, 256, 0, stream>>>(h_h, alpha, row_st, srcs, b1, graph, x1, Ah, E);

    // ---- Layer 2 ----
    transpose_cast<<<dim3(512 / 32, 512 / 32), tblk, 0, stream>>>(W2, Wt, 512, 512);
    gemm_f16<<<dim3(512 / BN, (N + BM - 1) / BM), 256, 0, stream>>>(Ah, Wt, h_h, N, 512, 512);
    attn_coef<<<(N * 4 + 3) / 4, 256, 0, stream>>>(h_h, as2, ad2, es, ed, N * 4, 4, 128);
    attn_alpha<<<(N * 4 + 3) / 4, 256, 0, stream>>>(es, ed, row_st, srcs, alpha, N, 4, E);
    aggregate3_concat<<<N, 256, 0, stream>>>(h_h, alpha, row_st, srcs, b2, x1, x2, Ah, E);

    // ---- Layer 3: HF=2, CF=512, mean, residual (no ELU) ----
    transpose_cast<<<dim3(1024 / 32, 512 / 32), tblk, 0, stream>>>(W3, Wt, 512, 1024);
    gemm_f16<<<dim3(1024 / BN, (N + BM - 1) / BM), 256, 0, stream>>>(Ah, Wt, h_h, N, 1024, 512);
    attn_coef<<<(N * 2 + 3) / 4, 256, 0, stream>>>(h_h, as3, ad3, es, ed, N * 2, 2, 512);
    attn_alpha<<<(N * 2 + 3) / 4, 256, 0, stream>>>(es, ed, row_st, srcs, alpha, N, 2, E);
    aggregate3_mean<<<N, 512, 0, stream>>>(h_h, alpha, row_st, srcs, b3, x2, (float*)d_out, E);
}

// Round 4
// 355.737 us; speedup vs baseline: 2.2612x; 1.0634x over previous
//
#include <hip/hip_runtime.h>
#include <hip/hip_bf16.h>
#include <hip/hip_fp16.h>
#include <cstddef>
#include <cstdint>

// ---------------------------------------------------------------------------
// GAT 3-layer network. R4: layer-3 restructured as aggregate-then-transform
// (gather x2 rows once, per-head weighted; GEMM with fused mean+bias+residual
// epilogue), packed single-gather alpha kernel, unrolled gather loops.
// ---------------------------------------------------------------------------

typedef _Float16 half8 __attribute__((ext_vector_type(8)));
typedef _Float16 half4v __attribute__((ext_vector_type(4)));
typedef float floatx4 __attribute__((ext_vector_type(4)));

#define AS1(p) ((const __attribute__((address_space(1))) void*)(p))
#define AS3(p) ((__attribute__((address_space(3))) void*)(p))

// ---------------- CSR build ----------------

__global__ void count_deg(const int* __restrict__ dst, int* __restrict__ deg, int E) {
    int e = blockIdx.x * blockDim.x + threadIdx.x;
    if (e < E) atomicAdd(&deg[dst[e]], 1);
}

__global__ void scan_kernel(const int* __restrict__ deg, int* __restrict__ row_start,
                            int* __restrict__ cursor, int n) {
    __shared__ int wsum[16];
    __shared__ int carry_s;
    int tid = threadIdx.x;              // 1024
    int wave = tid >> 6, lane = tid & 63;
    if (tid == 0) { carry_s = 0; row_start[0] = 0; }
    __syncthreads();
    for (int base = 0; base < n; base += 1024) {
        int i = base + tid;
        int v = (i < n) ? deg[i] : 0;
        int x = v;
#pragma unroll
        for (int off = 1; off < 64; off <<= 1) {
            int t = __shfl_up(x, off);
            if (lane >= off) x += t;
        }
        if (lane == 63) wsum[wave] = x;
        __syncthreads();
        if (wave == 0 && lane < 16) {
            int w = wsum[lane];
#pragma unroll
            for (int off = 1; off < 16; off <<= 1) {
                int t = __shfl_up(w, off);
                if (lane >= off) w += t;
            }
            wsum[lane] = w;
        }
        __syncthreads();
        int carry = carry_s;
        int incl = x + (wave ? wsum[wave - 1] : 0) + carry;
        if (i < n) { row_start[i + 1] = incl; cursor[i] = incl - v; }
        __syncthreads();
        if (tid == 1023) carry_s = incl;
        __syncthreads();
    }
}

__global__ void scatter_edges(const int* __restrict__ src, const int* __restrict__ dst,
                              int* __restrict__ cursor, int* __restrict__ srcs, int E) {
    int e = blockIdx.x * blockDim.x + threadIdx.x;
    if (e < E) {
        int p = atomicAdd(&cursor[dst[e]], 1);
        srcs[p] = src[e];
    }
}

// ---------------- casts ----------------

__global__ void cast_f16(const float* __restrict__ in, _Float16* __restrict__ out, int n4) {
    int i = blockIdx.x * blockDim.x + threadIdx.x;
    if (i < n4) {
        float4 v = ((const float4*)in)[i];
        half4v o = {(_Float16)v.x, (_Float16)v.y, (_Float16)v.z, (_Float16)v.w};
        ((half4v*)out)[i] = o;
    }
}

// out[c*out_ld + r] = (f16) in[r*in_ld + c]   for r<R, c<Cc (R,Cc mult of 32)
__global__ void transpose_cast_g(const float* __restrict__ in, _Float16* __restrict__ out,
                                 int R, int Cc, int in_ld, int out_ld) {
    __shared__ float t[32][33];
    int r0 = blockIdx.y * 32, c0 = blockIdx.x * 32;
    int tx = threadIdx.x, ty = threadIdx.y;   // 32 x 8
    for (int i = ty; i < 32; i += 8)
        t[i][tx] = in[(size_t)(r0 + i) * in_ld + c0 + tx];
    __syncthreads();
    for (int i = ty; i < 32; i += 8)
        out[(size_t)(c0 + i) * out_ld + r0 + tx] = (_Float16)t[tx][i];
}

// ---------------- MFMA GEMM: C[M,Nn] = A[M,K] @ Bt[Nn,K]^T, f16 in/out -----

#define BM 128
#define BN 128
#define BK 64

__global__ __launch_bounds__(256) void gemm_f16(const _Float16* __restrict__ A,
                                                const _Float16* __restrict__ Bt,
                                                _Float16* __restrict__ C,
                                                int M, int Nn, int K) {
    __shared__ _Float16 As[BM * BK];
    __shared__ _Float16 Bs[BN * BK];
    int tid = threadIdx.x;
    int lane = tid & 63, wave = tid >> 6;
    int wm = (wave & 1) * 64, wn = (wave >> 1) * 64;
    int m0 = blockIdx.y * BM, n0 = blockIdx.x * BN;
    int l15 = lane & 15, quad = lane >> 4;
    int trow = tid >> 3, tcol = tid & 7;

    floatx4 acc[4][4];
#pragma unroll
    for (int i = 0; i < 4; ++i)
#pragma unroll
        for (int j = 0; j < 4; ++j) acc[i][j] = (floatx4){0.f, 0.f, 0.f, 0.f};

    for (int k0 = 0; k0 < K; k0 += BK) {
        __syncthreads();
#pragma unroll
        for (int i = 0; i < 4; ++i) {
            int r = i * 32 + trow;
            int gr = m0 + r; if (gr >= M) gr = M - 1;
            const _Float16* gp = A + (size_t)gr * K + k0 + tcol * 8;
            _Float16* lp = As + (size_t)(i * 256 + tid) * 8;
            __builtin_amdgcn_global_load_lds(AS1(gp), AS3(lp), 16, 0, 0);
        }
#pragma unroll
        for (int i = 0; i < 4; ++i) {
            int r = i * 32 + trow;
            const _Float16* gp = Bt + (size_t)(n0 + r) * K + k0 + tcol * 8;
            _Float16* lp = Bs + (size_t)(i * 256 + tid) * 8;
            __builtin_amdgcn_global_load_lds(AS1(gp), AS3(lp), 16, 0, 0);
        }
        __syncthreads();
#pragma unroll
        for (int ks = 0; ks < BK; ks += 32) {
            half8 af[4], bfr[4];
#pragma unroll
            for (int i = 0; i < 4; ++i)
                af[i] = *(const half8*)&As[(wm + i * 16 + l15) * BK + ks + quad * 8];
#pragma unroll
            for (int j = 0; j < 4; ++j)
                bfr[j] = *(const half8*)&Bs[(wn + j * 16 + l15) * BK + ks + quad * 8];
#pragma unroll
            for (int i = 0; i < 4; ++i)
#pragma unroll
                for (int j = 0; j < 4; ++j)
                    acc[i][j] = __builtin_amdgcn_mfma_f32_16x16x32_f16(af[i], bfr[j], acc[i][j], 0, 0, 0);
        }
    }
#pragma unroll
    for (int i = 0; i < 4; ++i)
#pragma unroll
        for (int j = 0; j < 4; ++j) {
            int col = n0 + wn + j * 16 + l15;
#pragma unroll
            for (int r = 0; r < 4; ++r) {
                int row = m0 + wm + i * 16 + quad * 4 + r;
                if (row < M) C[(size_t)row * Nn + col] = (_Float16)acc[i][j][r];
            }
        }
}

// same GEMM, fp32 output with fused epilogue: out = 0.5*acc + bias[col] + xres
__global__ __launch_bounds__(256) void gemm_f16_ep(const _Float16* __restrict__ A,
                                                   const _Float16* __restrict__ Bt,
                                                   float* __restrict__ out,
                                                   const float* __restrict__ bias,
                                                   const float* __restrict__ xres,
                                                   int M, int Nn, int K) {
    __shared__ _Float16 As[BM * BK];
    __shared__ _Float16 Bs[BN * BK];
    int tid = threadIdx.x;
    int lane = tid & 63, wave = tid >> 6;
    int wm = (wave & 1) * 64, wn = (wave >> 1) * 64;
    int m0 = blockIdx.y * BM, n0 = blockIdx.x * BN;
    int l15 = lane & 15, quad = lane >> 4;
    int trow = tid >> 3, tcol = tid & 7;

    floatx4 acc[4][4];
#pragma unroll
    for (int i = 0; i < 4; ++i)
#pragma unroll
        for (int j = 0; j < 4; ++j) acc[i][j] = (floatx4){0.f, 0.f, 0.f, 0.f};

    for (int k0 = 0; k0 < K; k0 += BK) {
        __syncthreads();
#pragma unroll
        for (int i = 0; i < 4; ++i) {
            int r = i * 32 + trow;
            int gr = m0 + r; if (gr >= M) gr = M - 1;
            const _Float16* gp = A + (size_t)gr * K + k0 + tcol * 8;
            _Float16* lp = As + (size_t)(i * 256 + tid) * 8;
            __builtin_amdgcn_global_load_lds(AS1(gp), AS3(lp), 16, 0, 0);
        }
#pragma unroll
        for (int i = 0; i < 4; ++i) {
            int r = i * 32 + trow;
            const _Float16* gp = Bt + (size_t)(n0 + r) * K + k0 + tcol * 8;
            _Float16* lp = Bs + (size_t)(i * 256 + tid) * 8;
            __builtin_amdgcn_global_load_lds(AS1(gp), AS3(lp), 16, 0, 0);
        }
        __syncthreads();
#pragma unroll
        for (int ks = 0; ks < BK; ks += 32) {
            half8 af[4], bfr[4];
#pragma unroll
            for (int i = 0; i < 4; ++i)
                af[i] = *(const half8*)&As[(wm + i * 16 + l15) * BK + ks + quad * 8];
#pragma unroll
            for (int j = 0; j < 4; ++j)
                bfr[j] = *(const half8*)&Bs[(wn + j * 16 + l15) * BK + ks + quad * 8];
#pragma unroll
            for (int i = 0; i < 4; ++i)
#pragma unroll
                for (int j = 0; j < 4; ++j)
                    acc[i][j] = __builtin_amdgcn_mfma_f32_16x16x32_f16(af[i], bfr[j], acc[i][j], 0, 0, 0);
        }
    }
#pragma unroll
    for (int i = 0; i < 4; ++i)
#pragma unroll
        for (int j = 0; j < 4; ++j) {
            int col = n0 + wn + j * 16 + l15;
#pragma unroll
            for (int r = 0; r < 4; ++r) {
                int row = m0 + wm + i * 16 + quad * 4 + r;
                if (row < M)
                    out[(size_t)row * Nn + col] =
                        0.5f * acc[i][j][r] + bias[col] + xres[(size_t)row * Nn + col];
            }
        }
}

// ---------------- attention coefficients ----------------------------------
// rows are per (n,head): hp = h + gw*C   (layers 1/2, h = [N][H][C])
__global__ void attn_coef(const _Float16* __restrict__ h, const float* __restrict__ a_src,
                          const float* __restrict__ a_dst, float* __restrict__ es,
                          float* __restrict__ ed, int NH, int Hh, int C) {
    int gw = (blockIdx.x * blockDim.x + threadIdx.x) >> 6;
    int lane = threadIdx.x & 63;
    if (gw >= NH) return;
    int hd = gw % Hh;
    const _Float16* hp = h + (size_t)gw * C;
    const float* ap = a_src + hd * C;
    const float* dp = a_dst + hd * C;
    float ss = 0.f, sd = 0.f;
    for (int c = lane; c < C; c += 64) {
        float hv = (float)hp[c];
        ss += hv * ap[c];
        sd += hv * dp[c];
    }
#pragma unroll
    for (int off = 32; off; off >>= 1) {
        ss += __shfl_down(ss, off);
        sd += __shfl_down(sd, off);
    }
    if (lane == 0) { es[gw] = ss; ed[gw] = sd; }
}

// shared-row variant (layer 3): both heads dot the SAME x row with their own a
__global__ void attn_coef_shared(const _Float16* __restrict__ x, const float* __restrict__ a_src,
                                 const float* __restrict__ a_dst, float* __restrict__ es,
                                 float* __restrict__ ed, int NH, int Hh, int C) {
    int gw = (blockIdx.x * blockDim.x + threadIdx.x) >> 6;
    int lane = threadIdx.x & 63;
    if (gw >= NH) return;
    int n = gw / Hh, hd = gw - n * Hh;
    const _Float16* hp = x + (size_t)n * C;
    const float* ap = a_src + hd * C;
    const float* dp = a_dst + hd * C;
    float ss = 0.f, sd = 0.f;
    for (int c = lane; c < C; c += 64) {
        float hv = (float)hp[c];
        ss += hv * ap[c];
        sd += hv * dp[c];
    }
#pragma unroll
    for (int off = 32; off; off >>= 1) {
        ss += __shfl_down(ss, off);
        sd += __shfl_down(sd, off);
    }
    if (lane == 0) { es[gw] = ss; ed[gw] = sd; }
}

// layer-3 projected attention vectors: w[sel][h][k] = sum_c W3[k][h*512+c]*a[h][c]
__global__ void proj_a3(const float* __restrict__ W3, const float* __restrict__ as3,
                        const float* __restrict__ ad3, float* __restrict__ wes,
                        float* __restrict__ wed) {
    int gw = (blockIdx.x * blockDim.x + threadIdx.x) >> 6;   // 2048 waves
    int lane = threadIdx.x & 63;
    int k = gw & 511, h = (gw >> 9) & 1, sel = gw >> 10;
    const float* a = (sel ? ad3 : as3) + h * 512;
    const float* row = W3 + (size_t)k * 1024 + h * 512;
    float s = 0.f;
    for (int c = lane; c < 512; c += 64) s += row[c] * a[c];
#pragma unroll
    for (int off = 32; off; off >>= 1) s += __shfl_down(s, off);
    if (lane == 0) (sel ? wed : wes)[h * 512 + k] = s;
}

// ---------------- packed alpha: one wave per node, lane = eslot*H + h -------
// pass1 gathers es[src] once (stores leaky e into alpha), passes 2/3 coalesced.

template <int H>
__global__ __launch_bounds__(256) void attn_alpha_packed(
    const float* __restrict__ es, const float* __restrict__ ed,
    const int* __restrict__ row_start, const int* __restrict__ srcs,
    float* __restrict__ alpha, int Nn, int E) {
    const int EP = 64 / H;
    int wave = threadIdx.x >> 6, lane = threadIdx.x & 63;
    int n = blockIdx.x * 4 + wave;
    if (n >= Nn) return;
    int h = lane & (H - 1);
    int eslot = lane / H;
    float edn = ed[n * H + h];
    int beg = row_start[n], end = row_start[n + 1];
    float m = -INFINITY;
    for (int j0 = beg; j0 < end; j0 += EP) {
        int j = j0 + eslot;
        float e = -INFINITY;
        if (j < end) {
            e = es[srcs[j] * H + h] + edn;
            e = (e > 0.f) ? e : 0.2f * e;
            alpha[(size_t)h * E + j] = e;
        }
        m = fmaxf(m, e);
    }
#pragma unroll
    for (int off = H; off < 64; off <<= 1) m = fmaxf(m, __shfl_xor(m, off));
    float den = 0.f;
    for (int j0 = beg; j0 < end; j0 += EP) {
        int j = j0 + eslot;
        if (j < end) {
            float w = __expf(alpha[(size_t)h * E + j] - m);
            alpha[(size_t)h * E + j] = w;
            den += w;
        }
    }
#pragma unroll
    for (int off = H; off < 64; off <<= 1) den += __shfl_xor(den, off);
    float inv = 1.f / (den + 1e-16f);
    for (int j0 = beg; j0 < end; j0 += EP) {
        int j = j0 + eslot;
        if (j < end) alpha[(size_t)h * E + j] *= inv;
    }
}

// ---------------- aggregation (layers 1/2): gather h rows ------------------
// 256 thr = 4 slots x 64 lanes; lane covers 8 ch; unroll x2 for MLP.

__global__ __launch_bounds__(256) void aggregate3_concat(
    const _Float16* __restrict__ h, const float* __restrict__ alpha,
    const int* __restrict__ row_start, const int* __restrict__ srcs,
    const float* __restrict__ bias, const float* __restrict__ x_res,
    float* __restrict__ x_out, _Float16* __restrict__ x_out_h, int E) {
    __shared__ float red[4][512];
    int n = blockIdx.x;
    int tid = threadIdx.x;
    int slot = tid >> 6, lane = tid & 63;
    int head = lane >> 4;                 // C=128 -> 16 lanes per head
    int c0 = lane * 8;
    const float* al = alpha + (size_t)head * E;
    int beg = row_start[n], end = row_start[n + 1];
    float acc[8] = {};
    int j = beg + slot;
    for (; j + 4 < end; j += 8) {
        int s0 = srcs[j], s1 = srcs[j + 4];
        float w0 = al[j], w1 = al[j + 4];
        half8 h0 = *(const half8*)&h[(size_t)s0 * 512 + c0];
        half8 h1 = *(const half8*)&h[(size_t)s1 * 512 + c0];
#pragma unroll
        for (int k = 0; k < 8; ++k) acc[k] += w0 * (float)h0[k];
#pragma unroll
        for (int k = 0; k < 8; ++k) acc[k] += w1 * (float)h1[k];
    }
    if (j < end) {
        int s = srcs[j];
        float w = al[j];
        half8 hv = *(const half8*)&h[(size_t)s * 512 + c0];
#pragma unroll
        for (int k = 0; k < 8; ++k) acc[k] += w * (float)hv[k];
    }
#pragma unroll
    for (int k = 0; k < 8; ++k) red[slot][c0 + k] = acc[k];
    __syncthreads();
    int c = tid * 2;
    size_t base = (size_t)n * 512 + c;
    float v0 = red[0][c] + red[1][c] + red[2][c] + red[3][c] + bias[c] + x_res[base];
    float v1 = red[0][c + 1] + red[1][c + 1] + red[2][c + 1] + red[3][c + 1]
               + bias[c + 1] + x_res[base + 1];
    v0 = (v0 > 0.f) ? v0 : expm1f(v0);
    v1 = (v1 > 0.f) ? v1 : expm1f(v1);
    x_out[base] = v0;
    x_out[base + 1] = v1;
    x_out_h[base] = (_Float16)v0;
    x_out_h[base + 1] = (_Float16)v1;
}

// ---------------- aggregation (layer 3): gather x2 rows, dual head weights --
// y[n][h*512+c] = sum_e alpha[h][e] * x2[src_e][c]

__global__ __launch_bounds__(256) void aggregate_x_dual(
    const _Float16* __restrict__ x, const float* __restrict__ alpha,
    const int* __restrict__ row_start, const int* __restrict__ srcs,
    _Float16* __restrict__ y, int E) {
    __shared__ float red[4][1024];
    int n = blockIdx.x;
    int tid = threadIdx.x;
    int slot = tid >> 6, lane = tid & 63;
    int c0 = lane * 8;
    const float* al0 = alpha;
    const float* al1 = alpha + E;
    int beg = row_start[n], end = row_start[n + 1];
    float a0[8] = {}, a1[8] = {};
    int j = beg + slot;
    for (; j + 4 < end; j += 8) {
        int s0 = srcs[j], s1 = srcs[j + 4];
        float u0 = al0[j], v0 = al1[j];
        float u1 = al0[j + 4], v1 = al1[j + 4];
        half8 h0 = *(const half8*)&x[(size_t)s0 * 512 + c0];
        half8 h1 = *(const half8*)&x[(size_t)s1 * 512 + c0];
#pragma unroll
        for (int k = 0; k < 8; ++k) {
            float f = (float)h0[k];
            a0[k] += u0 * f;
            a1[k] += v0 * f;
        }
#pragma unroll
        for (int k = 0; k < 8; ++k) {
            float f = (float)h1[k];
            a0[k] += u1 * f;
            a1[k] += v1 * f;
        }
    }
    if (j < end) {
        int s = srcs[j];
        float u = al0[j], v = al1[j];
        half8 hv = *(const half8*)&x[(size_t)s * 512 + c0];
#pragma unroll
        for (int k = 0; k < 8; ++k) {
            float f = (float)hv[k];
            a0[k] += u * f;
            a1[k] += v * f;
        }
    }
#pragma unroll
    for (int k = 0; k < 8; ++k) {
        red[slot][c0 + k] = a0[k];
        red[slot][512 + c0 + k] = a1[k];
    }
    __syncthreads();
    int c = tid * 4;
    half4v o;
#pragma unroll
    for (int k = 0; k < 4; ++k)
        o[k] = (_Float16)(red[0][c + k] + red[1][c + k] + red[2][c + k] + red[3][c + k]);
    *(half4v*)&y[(size_t)n * 1024 + c] = o;
}

// ---------------------------------------------------------------------------

extern "C" void kernel_launch(void* const* d_in, const int* in_sizes, int n_in,
                              void* d_out, int out_size, void* d_ws, size_t ws_size,
                              hipStream_t stream) {
    const float* graph = (const float*)d_in[0];
    const int* edge_index = (const int*)d_in[1];
    const float* W1 = (const float*)d_in[2];
    const float* as1 = (const float*)d_in[3];
    const float* ad1 = (const float*)d_in[4];
    const float* b1 = (const float*)d_in[5];
    const float* W2 = (const float*)d_in[6];
    const float* as2 = (const float*)d_in[7];
    const float* ad2 = (const float*)d_in[8];
    const float* b2 = (const float*)d_in[9];
    const float* W3 = (const float*)d_in[10];
    const float* as3 = (const float*)d_in[11];
    const float* ad3 = (const float*)d_in[12];
    const float* b3 = (const float*)d_in[13];

    const int D = 512;
    int N = in_sizes[0] / D;       // 10000
    int E = in_sizes[1] / 2;       // 160000
    const int* src = edge_index;
    const int* dst = edge_index + E;

    char* p = (char*)d_ws;
    auto carve = [&](size_t bytes) {
        void* r = (void*)p;
        p += (bytes + 255) & ~(size_t)255;
        return r;
    };
    _Float16* Ah  = (_Float16*)carve((size_t)N * 512 * 2);    // x in f16 (reused per layer)
    _Float16* Wt  = (_Float16*)carve((size_t)512 * 512 * 2);  // layer-1/2 B^T
    _Float16* Bt3 = (_Float16*)carve((size_t)512 * 1024 * 2); // layer-3 stacked B^T
    _Float16* h_h = (_Float16*)carve((size_t)N * 1024 * 2);   // h (l1/2) / y (l3)
    float* x1     = (float*)carve((size_t)N * 512 * 4);
    float* x2     = (float*)carve((size_t)N * 512 * 4);
    float* es     = (float*)carve((size_t)N * 4 * 4);
    float* ed     = (float*)carve((size_t)N * 4 * 4);
    float* alpha  = (float*)carve((size_t)4 * E * 4);
    float* wes3   = (float*)carve((size_t)2 * 512 * 4);
    float* wed3   = (float*)carve((size_t)2 * 512 * 4);
    int* deg      = (int*)carve((size_t)N * 4);
    int* cur      = (int*)carve((size_t)N * 4);
    int* row_st   = (int*)carve((size_t)(N + 1) * 4);
    int* srcs     = (int*)carve((size_t)E * 4);

    // ---- CSR by dst (shared by all layers) ----
    hipMemsetAsync(deg, 0, (size_t)N * 4, stream);
    count_deg<<<(E + 255) / 256, 256, 0, stream>>>(dst, deg, E);
    scan_kernel<<<1, 1024, 0, stream>>>(deg, row_st, cur, N);
    scatter_edges<<<(E + 255) / 256, 256, 0, stream>>>(src, dst, cur, srcs, E);

    // ---- graph -> f16 ----
    cast_f16<<<(N * 512 / 4 + 255) / 256, 256, 0, stream>>>(graph, Ah, N * 512 / 4);

    dim3 tblk(32, 8);
    int nblk4 = (N + 3) / 4;
    // ---- Layer 1: H=4, C=128, concat, ELU + residual ----
    transpose_cast_g<<<dim3(16, 16), tblk, 0, stream>>>(W1, Wt, 512, 512, 512, 512);
    gemm_f16<<<dim3(512 / BN, (N + BM - 1) / BM), 256, 0, stream>>>(Ah, Wt, h_h, N, 512, 512);
    attn_coef<<<(N * 4 + 3) / 4, 256, 0, stream>>>(h_h, as1, ad1, es, ed, N * 4, 4, 128);
    attn_alpha_packed<4><<<nblk4, 256, 0, stream>>>(es, ed, row_st, srcs, alpha, N, E);
    aggregate3_concat<<<N, 256, 0, stream>>>(h_h, alpha, row_st, srcs, b1, graph, x1, Ah, E);

    // ---- Layer 2 ----
    transpose_cast_g<<<dim3(16, 16), tblk, 0, stream>>>(W2, Wt, 512, 512, 512, 512);
    gemm_f16<<<dim3(512 / BN, (N + BM - 1) / BM), 256, 0, stream>>>(Ah, Wt, h_h, N, 512, 512);
    attn_coef<<<(N * 4 + 3) / 4, 256, 0, stream>>>(h_h, as2, ad2, es, ed, N * 4, 4, 128);
    attn_alpha_packed<4><<<nblk4, 256, 0, stream>>>(es, ed, row_st, srcs, alpha, N, E);
    aggregate3_concat<<<N, 256, 0, stream>>>(h_h, alpha, row_st, srcs, b2, x1, x2, Ah, E);

    // ---- Layer 3: aggregate-then-transform ----
    // Bt3[cout][k]: k<512 -> W3[k][cout]; k>=512 -> W3[k-512][512+cout]
    transpose_cast_g<<<dim3(16, 16), tblk, 0, stream>>>(W3, Bt3, 512, 512, 1024, 1024);
    transpose_cast_g<<<dim3(16, 16), tblk, 0, stream>>>(W3 + 512, Bt3 + 512, 512, 512, 1024, 1024);
    proj_a3<<<512, 256, 0, stream>>>(W3, as3, ad3, wes3, wed3);
    attn_coef_shared<<<(N * 2 + 3) / 4, 256, 0, stream>>>(Ah, wes3, wed3, es, ed, N * 2, 2, 512);
    attn_alpha_packed<2><<<nblk4, 256, 0, stream>>>(es, ed, row_st, srcs, alpha, N, E);
    aggregate_x_dual<<<N, 256, 0, stream>>>(Ah, alpha, row_st, srcs, h_h, E);
    gemm_f16_ep<<<dim3(512 / BN, (N + BM - 1) / BM), 256, 0, stream>>>(
        h_h, Bt3, (float*)d_out, b3, x2, N, 512, 1024);
}

// Round 5
// 347.523 us; speedup vs baseline: 2.3147x; 1.0236x over previous
//
#include <hip/hip_runtime.h>
#include <hip/hip_bf16.h>
#include <hip/hip_fp16.h>
#include <cstddef>
#include <cstdint>

// ---------------------------------------------------------------------------
// GAT 3-layer network. R5: GEMMs retiled 128x128 -> 64x64 (grid 316 -> 1256
// blocks; R4 profile showed OccupancyPercent=10 on gemm_f16_ep — grid-starved)
// + 8-slot aggregation gathers.
// ---------------------------------------------------------------------------

typedef _Float16 half8 __attribute__((ext_vector_type(8)));
typedef _Float16 half4v __attribute__((ext_vector_type(4)));
typedef _Float16 half2v __attribute__((ext_vector_type(2)));
typedef float floatx4 __attribute__((ext_vector_type(4)));

#define AS1(p) ((const __attribute__((address_space(1))) void*)(p))
#define AS3(p) ((__attribute__((address_space(3))) void*)(p))

// ---------------- CSR build ----------------

__global__ void count_deg(const int* __restrict__ dst, int* __restrict__ deg, int E) {
    int e = blockIdx.x * blockDim.x + threadIdx.x;
    if (e < E) atomicAdd(&deg[dst[e]], 1);
}

__global__ void scan_kernel(const int* __restrict__ deg, int* __restrict__ row_start,
                            int* __restrict__ cursor, int n) {
    __shared__ int wsum[16];
    __shared__ int carry_s;
    int tid = threadIdx.x;              // 1024
    int wave = tid >> 6, lane = tid & 63;
    if (tid == 0) { carry_s = 0; row_start[0] = 0; }
    __syncthreads();
    for (int base = 0; base < n; base += 1024) {
        int i = base + tid;
        int v = (i < n) ? deg[i] : 0;
        int x = v;
#pragma unroll
        for (int off = 1; off < 64; off <<= 1) {
            int t = __shfl_up(x, off);
            if (lane >= off) x += t;
        }
        if (lane == 63) wsum[wave] = x;
        __syncthreads();
        if (wave == 0 && lane < 16) {
            int w = wsum[lane];
#pragma unroll
            for (int off = 1; off < 16; off <<= 1) {
                int t = __shfl_up(w, off);
                if (lane >= off) w += t;
            }
            wsum[lane] = w;
        }
        __syncthreads();
        int carry = carry_s;
        int incl = x + (wave ? wsum[wave - 1] : 0) + carry;
        if (i < n) { row_start[i + 1] = incl; cursor[i] = incl - v; }
        __syncthreads();
        if (tid == 1023) carry_s = incl;
        __syncthreads();
    }
}

__global__ void scatter_edges(const int* __restrict__ src, const int* __restrict__ dst,
                              int* __restrict__ cursor, int* __restrict__ srcs, int E) {
    int e = blockIdx.x * blockDim.x + threadIdx.x;
    if (e < E) {
        int p = atomicAdd(&cursor[dst[e]], 1);
        srcs[p] = src[e];
    }
}

// ---------------- casts ----------------

__global__ void cast_f16(const float* __restrict__ in, _Float16* __restrict__ out, int n4) {
    int i = blockIdx.x * blockDim.x + threadIdx.x;
    if (i < n4) {
        float4 v = ((const float4*)in)[i];
        half4v o = {(_Float16)v.x, (_Float16)v.y, (_Float16)v.z, (_Float16)v.w};
        ((half4v*)out)[i] = o;
    }
}

// out[c*out_ld + r] = (f16) in[r*in_ld + c]
__global__ void transpose_cast_g(const float* __restrict__ in, _Float16* __restrict__ out,
                                 int R, int Cc, int in_ld, int out_ld) {
    __shared__ float t[32][33];
    int r0 = blockIdx.y * 32, c0 = blockIdx.x * 32;
    int tx = threadIdx.x, ty = threadIdx.y;   // 32 x 8
    for (int i = ty; i < 32; i += 8)
        t[i][tx] = in[(size_t)(r0 + i) * in_ld + c0 + tx];
    __syncthreads();
    for (int i = ty; i < 32; i += 8)
        out[(size_t)(c0 + i) * out_ld + r0 + tx] = (_Float16)t[tx][i];
}

// ---------------- MFMA GEMM: C[M,Nn] = A[M,K] @ Bt[Nn,K]^T, 64x64 tile -----
// 4 waves of 32x32; grid (Nn/64, ceil(M/64)) — sized for skinny-N shapes.

#define BK 64

__global__ __launch_bounds__(256) void gemm_f16(const _Float16* __restrict__ A,
                                                const _Float16* __restrict__ Bt,
                                                _Float16* __restrict__ C,
                                                int M, int Nn, int K) {
    __shared__ _Float16 As[64 * BK];
    __shared__ _Float16 Bs[64 * BK];
    int tid = threadIdx.x;
    int lane = tid & 63, wave = tid >> 6;
    int wm = (wave & 1) * 32, wn = (wave >> 1) * 32;
    int m0 = blockIdx.y * 64, n0 = blockIdx.x * 64;
    int l15 = lane & 15, quad = lane >> 4;
    int trow = tid >> 3, tcol = tid & 7;      // 32 rows x 8 chunks of 16B

    floatx4 acc[2][2];
#pragma unroll
    for (int i = 0; i < 2; ++i)
#pragma unroll
        for (int j = 0; j < 2; ++j) acc[i][j] = (floatx4){0.f, 0.f, 0.f, 0.f};

    for (int k0 = 0; k0 < K; k0 += BK) {
        __syncthreads();
#pragma unroll
        for (int i = 0; i < 2; ++i) {
            int gr = m0 + i * 32 + trow; if (gr >= M) gr = M - 1;
            __builtin_amdgcn_global_load_lds(AS1(A + (size_t)gr * K + k0 + tcol * 8),
                                             AS3(As + (size_t)(i * 256 + tid) * 8), 16, 0, 0);
        }
#pragma unroll
        for (int i = 0; i < 2; ++i) {
            int gr = n0 + i * 32 + trow;
            __builtin_amdgcn_global_load_lds(AS1(Bt + (size_t)gr * K + k0 + tcol * 8),
                                             AS3(Bs + (size_t)(i * 256 + tid) * 8), 16, 0, 0);
        }
        __syncthreads();
#pragma unroll
        for (int ks = 0; ks < BK; ks += 32) {
            half8 af[2], bfr[2];
#pragma unroll
            for (int i = 0; i < 2; ++i)
                af[i] = *(const half8*)&As[(wm + i * 16 + l15) * BK + ks + quad * 8];
#pragma unroll
            for (int j = 0; j < 2; ++j)
                bfr[j] = *(const half8*)&Bs[(wn + j * 16 + l15) * BK + ks + quad * 8];
#pragma unroll
            for (int i = 0; i < 2; ++i)
#pragma unroll
                for (int j = 0; j < 2; ++j)
                    acc[i][j] = __builtin_amdgcn_mfma_f32_16x16x32_f16(af[i], bfr[j], acc[i][j], 0, 0, 0);
        }
    }
#pragma unroll
    for (int i = 0; i < 2; ++i)
#pragma unroll
        for (int j = 0; j < 2; ++j) {
            int col = n0 + wn + j * 16 + l15;
#pragma unroll
            for (int r = 0; r < 4; ++r) {
                int row = m0 + wm + i * 16 + quad * 4 + r;
                if (row < M) C[(size_t)row * Nn + col] = (_Float16)acc[i][j][r];
            }
        }
}

// same tile, fp32 output, fused epilogue: out = 0.5*acc + bias[col] + xres
__global__ __launch_bounds__(256) void gemm_f16_ep(const _Float16* __restrict__ A,
                                                   const _Float16* __restrict__ Bt,
                                                   float* __restrict__ out,
                                                   const float* __restrict__ bias,
                                                   const float* __restrict__ xres,
                                                   int M, int Nn, int K) {
    __shared__ _Float16 As[64 * BK];
    __shared__ _Float16 Bs[64 * BK];
    int tid = threadIdx.x;
    int lane = tid & 63, wave = tid >> 6;
    int wm = (wave & 1) * 32, wn = (wave >> 1) * 32;
    int m0 = blockIdx.y * 64, n0 = blockIdx.x * 64;
    int l15 = lane & 15, quad = lane >> 4;
    int trow = tid >> 3, tcol = tid & 7;

    floatx4 acc[2][2];
#pragma unroll
    for (int i = 0; i < 2; ++i)
#pragma unroll
        for (int j = 0; j < 2; ++j) acc[i][j] = (floatx4){0.f, 0.f, 0.f, 0.f};

    for (int k0 = 0; k0 < K; k0 += BK) {
        __syncthreads();
#pragma unroll
        for (int i = 0; i < 2; ++i) {
            int gr = m0 + i * 32 + trow; if (gr >= M) gr = M - 1;
            __builtin_amdgcn_global_load_lds(AS1(A + (size_t)gr * K + k0 + tcol * 8),
                                             AS3(As + (size_t)(i * 256 + tid) * 8), 16, 0, 0);
        }
#pragma unroll
        for (int i = 0; i < 2; ++i) {
            int gr = n0 + i * 32 + trow;
            __builtin_amdgcn_global_load_lds(AS1(Bt + (size_t)gr * K + k0 + tcol * 8),
                                             AS3(Bs + (size_t)(i * 256 + tid) * 8), 16, 0, 0);
        }
        __syncthreads();
#pragma unroll
        for (int ks = 0; ks < BK; ks += 32) {
            half8 af[2], bfr[2];
#pragma unroll
            for (int i = 0; i < 2; ++i)
                af[i] = *(const half8*)&As[(wm + i * 16 + l15) * BK + ks + quad * 8];
#pragma unroll
            for (int j = 0; j < 2; ++j)
                bfr[j] = *(const half8*)&Bs[(wn + j * 16 + l15) * BK + ks + quad * 8];
#pragma unroll
            for (int i = 0; i < 2; ++i)
#pragma unroll
                for (int j = 0; j < 2; ++j)
                    acc[i][j] = __builtin_amdgcn_mfma_f32_16x16x32_f16(af[i], bfr[j], acc[i][j], 0, 0, 0);
        }
    }
#pragma unroll
    for (int i = 0; i < 2; ++i)
#pragma unroll
        for (int j = 0; j < 2; ++j) {
            int col = n0 + wn + j * 16 + l15;
#pragma unroll
            for (int r = 0; r < 4; ++r) {
                int row = m0 + wm + i * 16 + quad * 4 + r;
                if (row < M)
                    out[(size_t)row * Nn + col] =
                        0.5f * acc[i][j][r] + bias[col] + xres[(size_t)row * Nn + col];
            }
        }
}

// ---------------- attention coefficients ----------------------------------

__global__ void attn_coef(const _Float16* __restrict__ h, const float* __restrict__ a_src,
                          const float* __restrict__ a_dst, float* __restrict__ es,
                          float* __restrict__ ed, int NH, int Hh, int C) {
    int gw = (blockIdx.x * blockDim.x + threadIdx.x) >> 6;
    int lane = threadIdx.x & 63;
    if (gw >= NH) return;
    int hd = gw % Hh;
    const _Float16* hp = h + (size_t)gw * C;
    const float* ap = a_src + hd * C;
    const float* dp = a_dst + hd * C;
    float ss = 0.f, sd = 0.f;
    for (int c = lane; c < C; c += 64) {
        float hv = (float)hp[c];
        ss += hv * ap[c];
        sd += hv * dp[c];
    }
#pragma unroll
    for (int off = 32; off; off >>= 1) {
        ss += __shfl_down(ss, off);
        sd += __shfl_down(sd, off);
    }
    if (lane == 0) { es[gw] = ss; ed[gw] = sd; }
}

// shared-row variant (layer 3): both heads dot the SAME x row with their own a
__global__ void attn_coef_shared(const _Float16* __restrict__ x, const float* __restrict__ a_src,
                                 const float* __restrict__ a_dst, float* __restrict__ es,
                                 float* __restrict__ ed, int NH, int Hh, int C) {
    int gw = (blockIdx.x * blockDim.x + threadIdx.x) >> 6;
    int lane = threadIdx.x & 63;
    if (gw >= NH) return;
    int n = gw / Hh, hd = gw - n * Hh;
    const _Float16* hp = x + (size_t)n * C;
    const float* ap = a_src + hd * C;
    const float* dp = a_dst + hd * C;
    float ss = 0.f, sd = 0.f;
    for (int c = lane; c < C; c += 64) {
        float hv = (float)hp[c];
        ss += hv * ap[c];
        sd += hv * dp[c];
    }
#pragma unroll
    for (int off = 32; off; off >>= 1) {
        ss += __shfl_down(ss, off);
        sd += __shfl_down(sd, off);
    }
    if (lane == 0) { es[gw] = ss; ed[gw] = sd; }
}

// layer-3 projected attention vectors: w[sel][h][k] = sum_c W3[k][h*512+c]*a[h][c]
__global__ void proj_a3(const float* __restrict__ W3, const float* __restrict__ as3,
                        const float* __restrict__ ad3, float* __restrict__ wes,
                        float* __restrict__ wed) {
    int gw = (blockIdx.x * blockDim.x + threadIdx.x) >> 6;   // 2048 waves
    int lane = threadIdx.x & 63;
    int k = gw & 511, h = (gw >> 9) & 1, sel = gw >> 10;
    const float* a = (sel ? ad3 : as3) + h * 512;
    const float* row = W3 + (size_t)k * 1024 + h * 512;
    float s = 0.f;
    for (int c = lane; c < 512; c += 64) s += row[c] * a[c];
#pragma unroll
    for (int off = 32; off; off >>= 1) s += __shfl_down(s, off);
    if (lane == 0) (sel ? wed : wes)[h * 512 + k] = s;
}

// ---------------- packed alpha: one wave per node, lane = eslot*H + h -------

template <int H>
__global__ __launch_bounds__(256) void attn_alpha_packed(
    const float* __restrict__ es, const float* __restrict__ ed,
    const int* __restrict__ row_start, const int* __restrict__ srcs,
    float* __restrict__ alpha, int Nn, int E) {
    const int EP = 64 / H;
    int wave = threadIdx.x >> 6, lane = threadIdx.x & 63;
    int n = blockIdx.x * 4 + wave;
    if (n >= Nn) return;
    int h = lane & (H - 1);
    int eslot = lane / H;
    float edn = ed[n * H + h];
    int beg = row_start[n], end = row_start[n + 1];
    float m = -INFINITY;
    for (int j0 = beg; j0 < end; j0 += EP) {
        int j = j0 + eslot;
        float e = -INFINITY;
        if (j < end) {
            e = es[srcs[j] * H + h] + edn;
            e = (e > 0.f) ? e : 0.2f * e;
            alpha[(size_t)h * E + j] = e;
        }
        m = fmaxf(m, e);
    }
#pragma unroll
    for (int off = H; off < 64; off <<= 1) m = fmaxf(m, __shfl_xor(m, off));
    float den = 0.f;
    for (int j0 = beg; j0 < end; j0 += EP) {
        int j = j0 + eslot;
        if (j < end) {
            float w = __expf(alpha[(size_t)h * E + j] - m);
            alpha[(size_t)h * E + j] = w;
            den += w;
        }
    }
#pragma unroll
    for (int off = H; off < 64; off <<= 1) den += __shfl_xor(den, off);
    float inv = 1.f / (den + 1e-16f);
    for (int j0 = beg; j0 < end; j0 += EP) {
        int j = j0 + eslot;
        if (j < end) alpha[(size_t)h * E + j] *= inv;
    }
}

// ---------------- aggregation (layers 1/2): 8 slots x 64 lanes -------------

__global__ __launch_bounds__(512) void aggregate3_concat(
    const _Float16* __restrict__ h, const float* __restrict__ alpha,
    const int* __restrict__ row_start, const int* __restrict__ srcs,
    const float* __restrict__ bias, const float* __restrict__ x_res,
    float* __restrict__ x_out, _Float16* __restrict__ x_out_h, int E) {
    __shared__ float red[8][512];
    int n = blockIdx.x;
    int tid = threadIdx.x;
    int slot = tid >> 6, lane = tid & 63;
    int head = lane >> 4;                 // C=128 -> 16 lanes per head
    int c0 = lane * 8;
    const float* al = alpha + (size_t)head * E;
    int beg = row_start[n], end = row_start[n + 1];
    float acc[8] = {};
    int j = beg + slot;
    for (; j + 8 < end; j += 16) {
        int s0 = srcs[j], s1 = srcs[j + 8];
        float w0 = al[j], w1 = al[j + 8];
        half8 h0 = *(const half8*)&h[(size_t)s0 * 512 + c0];
        half8 h1 = *(const half8*)&h[(size_t)s1 * 512 + c0];
#pragma unroll
        for (int k = 0; k < 8; ++k) acc[k] += w0 * (float)h0[k];
#pragma unroll
        for (int k = 0; k < 8; ++k) acc[k] += w1 * (float)h1[k];
    }
    if (j < end) {
        int s = srcs[j];
        float w = al[j];
        half8 hv = *(const half8*)&h[(size_t)s * 512 + c0];
#pragma unroll
        for (int k = 0; k < 8; ++k) acc[k] += w * (float)hv[k];
    }
#pragma unroll
    for (int k = 0; k < 8; ++k) red[slot][c0 + k] = acc[k];
    __syncthreads();
    int c = tid;
    size_t base = (size_t)n * 512 + c;
    float v = red[0][c] + red[1][c] + red[2][c] + red[3][c] +
              red[4][c] + red[5][c] + red[6][c] + red[7][c] + bias[c] + x_res[base];
    v = (v > 0.f) ? v : expm1f(v);
    x_out[base] = v;
    x_out_h[base] = (_Float16)v;
}

// ---------------- aggregation (layer 3): gather x2 rows, dual head weights --

__global__ __launch_bounds__(512) void aggregate_x_dual(
    const _Float16* __restrict__ x, const float* __restrict__ alpha,
    const int* __restrict__ row_start, const int* __restrict__ srcs,
    _Float16* __restrict__ y, int E) {
    __shared__ float red[8][1024];
    int n = blockIdx.x;
    int tid = threadIdx.x;
    int slot = tid >> 6, lane = tid & 63;
    int c0 = lane * 8;
    const float* al0 = alpha;
    const float* al1 = alpha + E;
    int beg = row_start[n], end = row_start[n + 1];
    float a0[8] = {}, a1[8] = {};
    int j = beg + slot;
    for (; j + 8 < end; j += 16) {
        int s0 = srcs[j], s1 = srcs[j + 8];
        float u0 = al0[j], v0 = al1[j];
        float u1 = al0[j + 8], v1 = al1[j + 8];
        half8 h0 = *(const half8*)&x[(size_t)s0 * 512 + c0];
        half8 h1 = *(const half8*)&x[(size_t)s1 * 512 + c0];
#pragma unroll
        for (int k = 0; k < 8; ++k) {
            float f = (float)h0[k];
            a0[k] += u0 * f;
            a1[k] += v0 * f;
        }
#pragma unroll
        for (int k = 0; k < 8; ++k) {
            float f = (float)h1[k];
            a0[k] += u1 * f;
            a1[k] += v1 * f;
        }
    }
    if (j < end) {
        int s = srcs[j];
        float u = al0[j], v = al1[j];
        half8 hv = *(const half8*)&x[(size_t)s * 512 + c0];
#pragma unroll
        for (int k = 0; k < 8; ++k) {
            float f = (float)hv[k];
            a0[k] += u * f;
            a1[k] += v * f;
        }
    }
#pragma unroll
    for (int k = 0; k < 8; ++k) {
        red[slot][c0 + k] = a0[k];
        red[slot][512 + c0 + k] = a1[k];
    }
    __syncthreads();
    int c = tid * 2;
    half2v o;
#pragma unroll
    for (int k = 0; k < 2; ++k) {
        float s = red[0][c + k] + red[1][c + k] + red[2][c + k] + red[3][c + k] +
                  red[4][c + k] + red[5][c + k] + red[6][c + k] + red[7][c + k];
        o[k] = (_Float16)s;
    }
    *(half2v*)&y[(size_t)n * 1024 + c] = o;
}

// ---------------------------------------------------------------------------

extern "C" void kernel_launch(void* const* d_in, const int* in_sizes, int n_in,
                              void* d_out, int out_size, void* d_ws, size_t ws_size,
                              hipStream_t stream) {
    const float* graph = (const float*)d_in[0];
    const int* edge_index = (const int*)d_in[1];
    const float* W1 = (const float*)d_in[2];
    const float* as1 = (const float*)d_in[3];
    const float* ad1 = (const float*)d_in[4];
    const float* b1 = (const float*)d_in[5];
    const float* W2 = (const float*)d_in[6];
    const float* as2 = (const float*)d_in[7];
    const float* ad2 = (const float*)d_in[8];
    const float* b2 = (const float*)d_in[9];
    const float* W3 = (const float*)d_in[10];
    const float* as3 = (const float*)d_in[11];
    const float* ad3 = (const float*)d_in[12];
    const float* b3 = (const float*)d_in[13];

    const int D = 512;
    int N = in_sizes[0] / D;       // 10000
    int E = in_sizes[1] / 2;       // 160000
    const int* src = edge_index;
    const int* dst = edge_index + E;

    char* p = (char*)d_ws;
    auto carve = [&](size_t bytes) {
        void* r = (void*)p;
        p += (bytes + 255) & ~(size_t)255;
        return r;
    };
    _Float16* Ah  = (_Float16*)carve((size_t)N * 512 * 2);    // x in f16 (reused per layer)
    _Float16* Wt  = (_Float16*)carve((size_t)512 * 512 * 2);  // layer-1/2 B^T
    _Float16* Bt3 = (_Float16*)carve((size_t)512 * 1024 * 2); // layer-3 stacked B^T
    _Float16* h_h = (_Float16*)carve((size_t)N * 1024 * 2);   // h (l1/2) / y (l3)
    float* x1     = (float*)carve((size_t)N * 512 * 4);
    float* x2     = (float*)carve((size_t)N * 512 * 4);
    float* es     = (float*)carve((size_t)N * 4 * 4);
    float* ed     = (float*)carve((size_t)N * 4 * 4);
    float* alpha  = (float*)carve((size_t)4 * E * 4);
    float* wes3   = (float*)carve((size_t)2 * 512 * 4);
    float* wed3   = (float*)carve((size_t)2 * 512 * 4);
    int* deg      = (int*)carve((size_t)N * 4);
    int* cur      = (int*)carve((size_t)N * 4);
    int* row_st   = (int*)carve((size_t)(N + 1) * 4);
    int* srcs     = (int*)carve((size_t)E * 4);

    // ---- CSR by dst (shared by all layers) ----
    hipMemsetAsync(deg, 0, (size_t)N * 4, stream);
    count_deg<<<(E + 255) / 256, 256, 0, stream>>>(dst, deg, E);
    scan_kernel<<<1, 1024, 0, stream>>>(deg, row_st, cur, N);
    scatter_edges<<<(E + 255) / 256, 256, 0, stream>>>(src, dst, cur, srcs, E);

    // ---- graph -> f16 ----
    cast_f16<<<(N * 512 / 4 + 255) / 256, 256, 0, stream>>>(graph, Ah, N * 512 / 4);

    dim3 tblk(32, 8);
    int nblk4 = (N + 3) / 4;
    int mblk = (N + 63) / 64;
    // ---- Layer 1: H=4, C=128, concat, ELU + residual ----
    transpose_cast_g<<<dim3(16, 16), tblk, 0, stream>>>(W1, Wt, 512, 512, 512, 512);
    gemm_f16<<<dim3(512 / 64, mblk), 256, 0, stream>>>(Ah, Wt, h_h, N, 512, 512);
    attn_coef<<<(N * 4 + 3) / 4, 256, 0, stream>>>(h_h, as1, ad1, es, ed, N * 4, 4, 128);
    attn_alpha_packed<4><<<nblk4, 256, 0, stream>>>(es, ed, row_st, srcs, alpha, N, E);
    aggregate3_concat<<<N, 512, 0, stream>>>(h_h, alpha, row_st, srcs, b1, graph, x1, Ah, E);

    // ---- Layer 2 ----
    transpose_cast_g<<<dim3(16, 16), tblk, 0, stream>>>(W2, Wt, 512, 512, 512, 512);
    gemm_f16<<<dim3(512 / 64, mblk), 256, 0, stream>>>(Ah, Wt, h_h, N, 512, 512);
    attn_coef<<<(N * 4 + 3) / 4, 256, 0, stream>>>(h_h, as2, ad2, es, ed, N * 4, 4, 128);
    attn_alpha_packed<4><<<nblk4, 256, 0, stream>>>(es, ed, row_st, srcs, alpha, N, E);
    aggregate3_concat<<<N, 512, 0, stream>>>(h_h, alpha, row_st, srcs, b2, x1, x2, Ah, E);

    // ---- Layer 3: aggregate-then-transform ----
    transpose_cast_g<<<dim3(16, 16), tblk, 0, stream>>>(W3, Bt3, 512, 512, 1024, 1024);
    transpose_cast_g<<<dim3(16, 16), tblk, 0, stream>>>(W3 + 512, Bt3 + 512, 512, 512, 1024, 1024);
    proj_a3<<<512, 256, 0, stream>>>(W3, as3, ad3, wes3, wed3);
    attn_coef_shared<<<(N * 2 + 3) / 4, 256, 0, stream>>>(Ah, wes3, wed3, es, ed, N * 2, 2, 512);
    attn_alpha_packed<2><<<nblk4, 256, 0, stream>>>(es, ed, row_st, srcs, alpha, N, E);
    aggregate_x_dual<<<N, 512, 0, stream>>>(Ah, alpha, row_st, srcs, h_h, E);
    gemm_f16_ep<<<dim3(512 / 64, mblk), 256, 0, stream>>>(
        h_h, Bt3, (float*)d_out, b3, x2, N, 512, 1024);
}

// Round 6
// 337.268 us; speedup vs baseline: 2.3851x; 1.0304x over previous
//
#include <hip/hip_runtime.h>
#include <hip/hip_bf16.h>
#include <hip/hip_fp16.h>
#include <cstddef>
#include <cstdint>

// ---------------------------------------------------------------------------
// GAT 3-layer network. R6: es/ed folded into GEMM extra columns, layer-3 coefs
// folded into layer-2 aggregate epilogue, f16 residuals (no fp32 x1/x2),
// 2-pass alpha with deferred normalization, single prep kernel.
// ---------------------------------------------------------------------------

typedef _Float16 half8 __attribute__((ext_vector_type(8)));
typedef _Float16 half4v __attribute__((ext_vector_type(4)));
typedef _Float16 half2v __attribute__((ext_vector_type(2)));
typedef float floatx4 __attribute__((ext_vector_type(4)));

#define AS1(p) ((const __attribute__((address_space(1))) void*)(p))
#define AS3(p) ((__attribute__((address_space(3))) void*)(p))

// ---------------- CSR build ----------------

__global__ void count_deg(const int* __restrict__ dst, int* __restrict__ deg, int E) {
    int e = blockIdx.x * blockDim.x + threadIdx.x;
    if (e < E) atomicAdd(&deg[dst[e]], 1);
}

__global__ void scan_kernel(const int* __restrict__ deg, int* __restrict__ row_start,
                            int* __restrict__ cursor, int n) {
    __shared__ int wsum[16];
    __shared__ int carry_s;
    int tid = threadIdx.x;              // 1024
    int wave = tid >> 6, lane = tid & 63;
    if (tid == 0) { carry_s = 0; row_start[0] = 0; }
    __syncthreads();
    for (int base = 0; base < n; base += 1024) {
        int i = base + tid;
        int v = (i < n) ? deg[i] : 0;
        int x = v;
#pragma unroll
        for (int off = 1; off < 64; off <<= 1) {
            int t = __shfl_up(x, off);
            if (lane >= off) x += t;
        }
        if (lane == 63) wsum[wave] = x;
        __syncthreads();
        if (wave == 0 && lane < 16) {
            int w = wsum[lane];
#pragma unroll
            for (int off = 1; off < 16; off <<= 1) {
                int t = __shfl_up(w, off);
                if (lane >= off) w += t;
            }
            wsum[lane] = w;
        }
        __syncthreads();
        int carry = carry_s;
        int incl = x + (wave ? wsum[wave - 1] : 0) + carry;
        if (i < n) { row_start[i + 1] = incl; cursor[i] = incl - v; }
        __syncthreads();
        if (tid == 1023) carry_s = incl;
        __syncthreads();
    }
}

__global__ void scatter_edges(const int* __restrict__ src, const int* __restrict__ dst,
                              int* __restrict__ cursor, int* __restrict__ srcs, int E) {
    int e = blockIdx.x * blockDim.x + threadIdx.x;
    if (e < E) {
        int p = atomicAdd(&cursor[dst[e]], 1);
        srcs[p] = src[e];
    }
}

// ---------------- casts / prep ----------------

__global__ void cast_f16(const float* __restrict__ in, _Float16* __restrict__ out, int n4) {
    int i = blockIdx.x * blockDim.x + threadIdx.x;
    if (i < n4) {
        float4 v = ((const float4*)in)[i];
        half4v o = {(_Float16)v.x, (_Float16)v.y, (_Float16)v.z, (_Float16)v.w};
        ((half4v*)out)[i] = o;
    }
}

// out[c*out_ld + r] = (f16) in[r*in_ld + c]
__global__ void transpose_cast_g(const float* __restrict__ in, _Float16* __restrict__ out,
                                 int in_ld, int out_ld) {
    __shared__ float t[32][33];
    int r0 = blockIdx.y * 32, c0 = blockIdx.x * 32;
    int tx = threadIdx.x, ty = threadIdx.y;   // 32 x 8
    for (int i = ty; i < 32; i += 8)
        t[i][tx] = in[(size_t)(r0 + i) * in_ld + c0 + tx];
    __syncthreads();
    for (int i = ty; i < 32; i += 8)
        out[(size_t)(c0 + i) * out_ld + r0 + tx] = (_Float16)t[tx][i];
}

// one kernel: attention-projection rows for Wt1/Wt2 (rows 512..519),
// wes3/wed3 for layer 3, and zero-fill of Wt pad rows 520..575.
__global__ void proj_all(const float* __restrict__ W1, const float* __restrict__ as1,
                         const float* __restrict__ ad1,
                         const float* __restrict__ W2, const float* __restrict__ as2,
                         const float* __restrict__ ad2,
                         const float* __restrict__ W3, const float* __restrict__ as3,
                         const float* __restrict__ ad3,
                         _Float16* __restrict__ Wt1, _Float16* __restrict__ Wt2,
                         float* __restrict__ wes3, float* __restrict__ wed3) {
    int w = (blockIdx.x * blockDim.x + threadIdx.x) >> 6;
    int lane = threadIdx.x & 63;
    if (w < 8192) {                       // Wt1/Wt2 attn rows: 2 layers x 2 sel x 4 h x 512 d
        int layer = w >> 12;
        int idx = w & 4095;
        int d = idx & 511, hh = (idx >> 9) & 3, sel = idx >> 11;
        const float* W = layer ? W2 : W1;
        const float* a = layer ? (sel ? ad2 : as2) : (sel ? ad1 : as1);
        const float* row = W + (size_t)d * 512 + hh * 128;
        const float* av = a + hh * 128;
        float s = 0.f;
        s += row[lane] * av[lane];
        s += row[lane + 64] * av[lane + 64];
#pragma unroll
        for (int off = 32; off; off >>= 1) s += __shfl_down(s, off);
        if (lane == 0) {
            _Float16* Wt = layer ? Wt2 : Wt1;
            Wt[(size_t)(512 + sel * 4 + hh) * 512 + d] = (_Float16)s;
        }
    } else if (w < 10240) {               // layer-3 projections: 2 sel x 2 h x 512 k
        int idx = w - 8192;
        int k = idx & 511, hh = (idx >> 9) & 1, sel = idx >> 10;
        const float* a = (sel ? ad3 : as3) + hh * 512;
        const float* row = W3 + (size_t)k * 1024 + hh * 512;
        float s = 0.f;
        for (int c = lane; c < 512; c += 64) s += row[c] * a[c];
#pragma unroll
        for (int off = 32; off; off >>= 1) s += __shfl_down(s, off);
        if (lane == 0) (sel ? wed3 : wes3)[hh * 512 + k] = s;
    } else if (w < 11136) {               // zero-fill Wt pad rows 520..575 (both layers)
        int z = (w - 10240) * 64 + lane;  // 0..57343
        int layer = z / 28672;
        int rem = z - layer * 28672;
        int row = 520 + rem / 512, col = rem & 511;
        (layer ? Wt2 : Wt1)[(size_t)row * 512 + col] = (_Float16)0.f;
    }
}

// ---------------- MFMA GEMM (64x64 tile, 4 waves of 32x32) -----------------

#define BK 64

// layers 1/2: Nn=576 fixed; cols 0..511 -> h (f16, ld 512); 512..515 -> es;
// 516..519 -> ed; 520..575 discarded.
__global__ __launch_bounds__(256) void gemm_f16_att(const _Float16* __restrict__ A,
                                                    const _Float16* __restrict__ Bt,
                                                    _Float16* __restrict__ Hout,
                                                    float* __restrict__ es,
                                                    float* __restrict__ ed,
                                                    int M, int K) {
    __shared__ _Float16 As[64 * BK];
    __shared__ _Float16 Bs[64 * BK];
    int tid = threadIdx.x;
    int lane = tid & 63, wave = tid >> 6;
    int wm = (wave & 1) * 32, wn = (wave >> 1) * 32;
    int m0 = blockIdx.y * 64, n0 = blockIdx.x * 64;
    int l15 = lane & 15, quad = lane >> 4;
    int trow = tid >> 3, tcol = tid & 7;

    floatx4 acc[2][2];
#pragma unroll
    for (int i = 0; i < 2; ++i)
#pragma unroll
        for (int j = 0; j < 2; ++j) acc[i][j] = (floatx4){0.f, 0.f, 0.f, 0.f};

    for (int k0 = 0; k0 < K; k0 += BK) {
        __syncthreads();
#pragma unroll
        for (int i = 0; i < 2; ++i) {
            int gr = m0 + i * 32 + trow; if (gr >= M) gr = M - 1;
            __builtin_amdgcn_global_load_lds(AS1(A + (size_t)gr * K + k0 + tcol * 8),
                                             AS3(As + (size_t)(i * 256 + tid) * 8), 16, 0, 0);
        }
#pragma unroll
        for (int i = 0; i < 2; ++i) {
            int gr = n0 + i * 32 + trow;
            __builtin_amdgcn_global_load_lds(AS1(Bt + (size_t)gr * K + k0 + tcol * 8),
                                             AS3(Bs + (size_t)(i * 256 + tid) * 8), 16, 0, 0);
        }
        __syncthreads();
#pragma unroll
        for (int ks = 0; ks < BK; ks += 32) {
            half8 af[2], bfr[2];
#pragma unroll
            for (int i = 0; i < 2; ++i)
                af[i] = *(const half8*)&As[(wm + i * 16 + l15) * BK + ks + quad * 8];
#pragma unroll
            for (int j = 0; j < 2; ++j)
                bfr[j] = *(const half8*)&Bs[(wn + j * 16 + l15) * BK + ks + quad * 8];
#pragma unroll
            for (int i = 0; i < 2; ++i)
#pragma unroll
                for (int j = 0; j < 2; ++j)
                    acc[i][j] = __builtin_amdgcn_mfma_f32_16x16x32_f16(af[i], bfr[j], acc[i][j], 0, 0, 0);
        }
    }
#pragma unroll
    for (int i = 0; i < 2; ++i)
#pragma unroll
        for (int j = 0; j < 2; ++j) {
            int col = n0 + wn + j * 16 + l15;
#pragma unroll
            for (int r = 0; r < 4; ++r) {
                int row = m0 + wm + i * 16 + quad * 4 + r;
                if (row < M) {
                    float v = acc[i][j][r];
                    if (col < 512) Hout[(size_t)row * 512 + col] = (_Float16)v;
                    else if (col < 516) es[row * 4 + col - 512] = v;
                    else if (col < 520) ed[row * 4 + col - 516] = v;
                }
            }
        }
}

// layer 3: fp32 out, fused epilogue: out = 0.5*acc + bias[col] + (f32)xres16
__global__ __launch_bounds__(256) void gemm_f16_ep(const _Float16* __restrict__ A,
                                                   const _Float16* __restrict__ Bt,
                                                   float* __restrict__ out,
                                                   const float* __restrict__ bias,
                                                   const _Float16* __restrict__ xres,
                                                   int M, int Nn, int K) {
    __shared__ _Float16 As[64 * BK];
    __shared__ _Float16 Bs[64 * BK];
    int tid = threadIdx.x;
    int lane = tid & 63, wave = tid >> 6;
    int wm = (wave & 1) * 32, wn = (wave >> 1) * 32;
    int m0 = blockIdx.y * 64, n0 = blockIdx.x * 64;
    int l15 = lane & 15, quad = lane >> 4;
    int trow = tid >> 3, tcol = tid & 7;

    floatx4 acc[2][2];
#pragma unroll
    for (int i = 0; i < 2; ++i)
#pragma unroll
        for (int j = 0; j < 2; ++j) acc[i][j] = (floatx4){0.f, 0.f, 0.f, 0.f};

    for (int k0 = 0; k0 < K; k0 += BK) {
        __syncthreads();
#pragma unroll
        for (int i = 0; i < 2; ++i) {
            int gr = m0 + i * 32 + trow; if (gr >= M) gr = M - 1;
            __builtin_amdgcn_global_load_lds(AS1(A + (size_t)gr * K + k0 + tcol * 8),
                                             AS3(As + (size_t)(i * 256 + tid) * 8), 16, 0, 0);
        }
#pragma unroll
        for (int i = 0; i < 2; ++i) {
            int gr = n0 + i * 32 + trow;
            __builtin_amdgcn_global_load_lds(AS1(Bt + (size_t)gr * K + k0 + tcol * 8),
                                             AS3(Bs + (size_t)(i * 256 + tid) * 8), 16, 0, 0);
        }
        __syncthreads();
#pragma unroll
        for (int ks = 0; ks < BK; ks += 32) {
            half8 af[2], bfr[2];
#pragma unroll
            for (int i = 0; i < 2; ++i)
                af[i] = *(const half8*)&As[(wm + i * 16 + l15) * BK + ks + quad * 8];
#pragma unroll
            for (int j = 0; j < 2; ++j)
                bfr[j] = *(const half8*)&Bs[(wn + j * 16 + l15) * BK + ks + quad * 8];
#pragma unroll
            for (int i = 0; i < 2; ++i)
#pragma unroll
                for (int j = 0; j < 2; ++j)
                    acc[i][j] = __builtin_amdgcn_mfma_f32_16x16x32_f16(af[i], bfr[j], acc[i][j], 0, 0, 0);
        }
    }
#pragma unroll
    for (int i = 0; i < 2; ++i)
#pragma unroll
        for (int j = 0; j < 2; ++j) {
            int col = n0 + wn + j * 16 + l15;
#pragma unroll
            for (int r = 0; r < 4; ++r) {
                int row = m0 + wm + i * 16 + quad * 4 + r;
                if (row < M)
                    out[(size_t)row * Nn + col] =
                        0.5f * acc[i][j][r] + bias[col] + (float)xres[(size_t)row * Nn + col];
            }
        }
}

// ---------------- alpha: 2 passes, unnormalized exp + den ------------------
// one wave per node; lane = eslot*H + h.

template <int H>
__global__ __launch_bounds__(256) void attn_alpha2(
    const float* __restrict__ es, const float* __restrict__ ed,
    const int* __restrict__ row_start, const int* __restrict__ srcs,
    float* __restrict__ alpha, float* __restrict__ den, int Nn, int E) {
    const int EP = 64 / H;
    int wave = threadIdx.x >> 6, lane = threadIdx.x & 63;
    int n = blockIdx.x * 4 + wave;
    if (n >= Nn) return;
    int h = lane & (H - 1);
    int eslot = lane / H;
    float edn = ed[n * H + h];
    int beg = row_start[n], end = row_start[n + 1];
    float m = -INFINITY;
    for (int j0 = beg; j0 < end; j0 += EP) {
        int j = j0 + eslot;
        float e = -INFINITY;
        if (j < end) {
            e = es[srcs[j] * H + h] + edn;
            e = (e > 0.f) ? e : 0.2f * e;
            alpha[(size_t)h * E + j] = e;
        }
        m = fmaxf(m, e);
    }
#pragma unroll
    for (int off = H; off < 64; off <<= 1) m = fmaxf(m, __shfl_xor(m, off));
    float dsum = 0.f;
    for (int j0 = beg; j0 < end; j0 += EP) {
        int j = j0 + eslot;
        if (j < end) {
            float w = __expf(alpha[(size_t)h * E + j] - m);
            alpha[(size_t)h * E + j] = w;
            dsum += w;
        }
    }
#pragma unroll
    for (int off = H; off < 64; off <<= 1) dsum += __shfl_xor(dsum, off);
    if (lane < H) den[n * H + lane] = dsum;
}

// ---------------- aggregation (layers 1/2): 8 slots x 64 lanes -------------
// RES32: residual fp32 (layer 1, graph). COEF3: also emit layer-3 es/ed.

template <bool RES32, bool COEF3>
__global__ __launch_bounds__(512) void aggregate4_concat(
    const _Float16* __restrict__ h, const float* __restrict__ alpha,
    const float* __restrict__ den,
    const int* __restrict__ row_start, const int* __restrict__ srcs,
    const float* __restrict__ bias, const float* __restrict__ xres32,
    const _Float16* __restrict__ xres16, _Float16* __restrict__ x_out_h,
    const float* __restrict__ wes3, const float* __restrict__ wed3,
    float* __restrict__ es3, float* __restrict__ ed3, int E) {
    __shared__ float red[8][512];
    __shared__ float csum[8][4];
    int n = blockIdx.x;
    int tid = threadIdx.x;
    int slot = tid >> 6, lane = tid & 63;
    int head = lane >> 4;                 // C=128 -> 16 lanes per head
    int c0 = lane * 8;
    const float* al = alpha + (size_t)head * E;
    int beg = row_start[n], end = row_start[n + 1];
    float acc[8] = {};
    int j = beg + slot;
    for (; j + 8 < end; j += 16) {
        int s0 = srcs[j], s1 = srcs[j + 8];
        float w0 = al[j], w1 = al[j + 8];
        half8 h0 = *(const half8*)&h[(size_t)s0 * 512 + c0];
        half8 h1 = *(const half8*)&h[(size_t)s1 * 512 + c0];
#pragma unroll
        for (int k = 0; k < 8; ++k) acc[k] += w0 * (float)h0[k];
#pragma unroll
        for (int k = 0; k < 8; ++k) acc[k] += w1 * (float)h1[k];
    }
    if (j < end) {
        int s = srcs[j];
        float w = al[j];
        half8 hv = *(const half8*)&h[(size_t)s * 512 + c0];
#pragma unroll
        for (int k = 0; k < 8; ++k) acc[k] += w * (float)hv[k];
    }
#pragma unroll
    for (int k = 0; k < 8; ++k) red[slot][c0 + k] = acc[k];
    __syncthreads();
    int c = tid;
    float invden = 1.f / (den[n * 4 + (c >> 7)] + 1e-16f);
    float s = red[0][c] + red[1][c] + red[2][c] + red[3][c] +
              red[4][c] + red[5][c] + red[6][c] + red[7][c];
    size_t base = (size_t)n * 512 + c;
    float res = RES32 ? xres32[base] : (float)xres16[base];
    float v = s * invden + bias[c] + res;
    v = (v > 0.f) ? v : expm1f(v);
    x_out_h[base] = (_Float16)v;
    if (COEF3) {
        float t0 = v * wes3[c], t1 = v * wes3[512 + c];
        float t2 = v * wed3[c], t3 = v * wed3[512 + c];
#pragma unroll
        for (int off = 32; off; off >>= 1) {
            t0 += __shfl_down(t0, off);
            t1 += __shfl_down(t1, off);
            t2 += __shfl_down(t2, off);
            t3 += __shfl_down(t3, off);
        }
        if (lane == 0) {
            csum[slot][0] = t0; csum[slot][1] = t1;
            csum[slot][2] = t2; csum[slot][3] = t3;
        }
        __syncthreads();
        if (tid == 0) {
            float a0 = 0, a1 = 0, a2 = 0, a3 = 0;
#pragma unroll
            for (int w = 0; w < 8; ++w) {
                a0 += csum[w][0]; a1 += csum[w][1];
                a2 += csum[w][2]; a3 += csum[w][3];
            }
            es3[n * 2] = a0; es3[n * 2 + 1] = a1;
            ed3[n * 2] = a2; ed3[n * 2 + 1] = a3;
        }
    }
}

// ---------------- aggregation (layer 3): gather x2 rows, dual head weights --

__global__ __launch_bounds__(512) void aggregate_x_dual(
    const _Float16* __restrict__ x, const float* __restrict__ alpha,
    const float* __restrict__ den,
    const int* __restrict__ row_start, const int* __restrict__ srcs,
    _Float16* __restrict__ y, int E) {
    __shared__ float red[8][1024];
    int n = blockIdx.x;
    int tid = threadIdx.x;
    int slot = tid >> 6, lane = tid & 63;
    int c0 = lane * 8;
    const float* al0 = alpha;
    const float* al1 = alpha + E;
    int beg = row_start[n], end = row_start[n + 1];
    float a0[8] = {}, a1[8] = {};
    int j = beg + slot;
    for (; j + 8 < end; j += 16) {
        int s0 = srcs[j], s1 = srcs[j + 8];
        float u0 = al0[j], v0 = al1[j];
        float u1 = al0[j + 8], v1 = al1[j + 8];
        half8 h0 = *(const half8*)&x[(size_t)s0 * 512 + c0];
        half8 h1 = *(const half8*)&x[(size_t)s1 * 512 + c0];
#pragma unroll
        for (int k = 0; k < 8; ++k) {
            float f = (float)h0[k];
            a0[k] += u0 * f;
            a1[k] += v0 * f;
        }
#pragma unroll
        for (int k = 0; k < 8; ++k) {
            float f = (float)h1[k];
            a0[k] += u1 * f;
            a1[k] += v1 * f;
        }
    }
    if (j < end) {
        int s = srcs[j];
        float u = al0[j], v = al1[j];
        half8 hv = *(const half8*)&x[(size_t)s * 512 + c0];
#pragma unroll
        for (int k = 0; k < 8; ++k) {
            float f = (float)hv[k];
            a0[k] += u * f;
            a1[k] += v * f;
        }
    }
#pragma unroll
    for (int k = 0; k < 8; ++k) {
        red[slot][c0 + k] = a0[k];
        red[slot][512 + c0 + k] = a1[k];
    }
    __syncthreads();
    float invd0 = 1.f / (den[n * 2] + 1e-16f);
    float invd1 = 1.f / (den[n * 2 + 1] + 1e-16f);
    int c = tid * 2;
    float inv = (c < 512) ? invd0 : invd1;
    half2v o;
#pragma unroll
    for (int k = 0; k < 2; ++k) {
        float s = red[0][c + k] + red[1][c + k] + red[2][c + k] + red[3][c + k] +
                  red[4][c + k] + red[5][c + k] + red[6][c + k] + red[7][c + k];
        o[k] = (_Float16)(s * inv);
    }
    *(half2v*)&y[(size_t)n * 1024 + c] = o;
}

// ---------------------------------------------------------------------------

extern "C" void kernel_launch(void* const* d_in, const int* in_sizes, int n_in,
                              void* d_out, int out_size, void* d_ws, size_t ws_size,
                              hipStream_t stream) {
    const float* graph = (const float*)d_in[0];
    const int* edge_index = (const int*)d_in[1];
    const float* W1 = (const float*)d_in[2];
    const float* as1 = (const float*)d_in[3];
    const float* ad1 = (const float*)d_in[4];
    const float* b1 = (const float*)d_in[5];
    const float* W2 = (const float*)d_in[6];
    const float* as2 = (const float*)d_in[7];
    const float* ad2 = (const float*)d_in[8];
    const float* b2 = (const float*)d_in[9];
    const float* W3 = (const float*)d_in[10];
    const float* as3 = (const float*)d_in[11];
    const float* ad3 = (const float*)d_in[12];
    const float* b3 = (const float*)d_in[13];

    const int D = 512;
    int N = in_sizes[0] / D;       // 10000
    int E = in_sizes[1] / 2;       // 160000
    const int* src = edge_index;
    const int* dst = edge_index + E;

    char* p = (char*)d_ws;
    auto carve = [&](size_t bytes) {
        void* r = (void*)p;
        p += (bytes + 255) & ~(size_t)255;
        return r;
    };
    _Float16* Ah   = (_Float16*)carve((size_t)N * 512 * 2);    // x (f16), rewritten per layer
    _Float16* Wt1  = (_Float16*)carve((size_t)576 * 512 * 2);  // W1^T + attn rows + pad
    _Float16* Wt2  = (_Float16*)carve((size_t)576 * 512 * 2);
    _Float16* Bt3  = (_Float16*)carve((size_t)512 * 1024 * 2); // layer-3 stacked B^T
    _Float16* h_h  = (_Float16*)carve((size_t)N * 1024 * 2);   // h (l1/2, ld 512) / y (l3, ld 1024)
    float* es      = (float*)carve((size_t)N * 4 * 4);
    float* ed      = (float*)carve((size_t)N * 4 * 4);
    float* den     = (float*)carve((size_t)N * 4 * 4);
    float* alpha   = (float*)carve((size_t)4 * E * 4);
    float* wes3    = (float*)carve((size_t)2 * 512 * 4);
    float* wed3    = (float*)carve((size_t)2 * 512 * 4);
    int* deg       = (int*)carve((size_t)N * 4);
    int* cur       = (int*)carve((size_t)N * 4);
    int* row_st    = (int*)carve((size_t)(N + 1) * 4);
    int* srcs      = (int*)carve((size_t)E * 4);

    // ---- CSR by dst (shared by all layers) ----
    hipMemsetAsync(deg, 0, (size_t)N * 4, stream);
    count_deg<<<(E + 255) / 256, 256, 0, stream>>>(dst, deg, E);
    scan_kernel<<<1, 1024, 0, stream>>>(deg, row_st, cur, N);
    scatter_edges<<<(E + 255) / 256, 256, 0, stream>>>(src, dst, cur, srcs, E);

    // ---- prep: casts, weight transposes, attention projections ----
    cast_f16<<<(N * 512 / 4 + 255) / 256, 256, 0, stream>>>(graph, Ah, N * 512 / 4);
    dim3 tblk(32, 8);
    transpose_cast_g<<<dim3(16, 16), tblk, 0, stream>>>(W1, Wt1, 512, 512);
    transpose_cast_g<<<dim3(16, 16), tblk, 0, stream>>>(W2, Wt2, 512, 512);
    transpose_cast_g<<<dim3(16, 16), tblk, 0, stream>>>(W3, Bt3, 1024, 1024);
    transpose_cast_g<<<dim3(16, 16), tblk, 0, stream>>>(W3 + 512, Bt3 + 512, 1024, 1024);
    proj_all<<<2784, 256, 0, stream>>>(W1, as1, ad1, W2, as2, ad2, W3, as3, ad3,
                                       Wt1, Wt2, wes3, wed3);

    int nblk4 = (N + 3) / 4;
    int mblk = (N + 63) / 64;
    // ---- Layer 1 ----
    gemm_f16_att<<<dim3(9, mblk), 256, 0, stream>>>(Ah, Wt1, h_h, es, ed, N, 512);
    attn_alpha2<4><<<nblk4, 256, 0, stream>>>(es, ed, row_st, srcs, alpha, den, N, E);
    aggregate4_concat<true, false><<<N, 512, 0, stream>>>(
        h_h, alpha, den, row_st, srcs, b1, graph, nullptr, Ah,
        nullptr, nullptr, nullptr, nullptr, E);

    // ---- Layer 2 (also emits layer-3 es/ed) ----
    gemm_f16_att<<<dim3(9, mblk), 256, 0, stream>>>(Ah, Wt2, h_h, es, ed, N, 512);
    attn_alpha2<4><<<nblk4, 256, 0, stream>>>(es, ed, row_st, srcs, alpha, den, N, E);
    aggregate4_concat<false, true><<<N, 512, 0, stream>>>(
        h_h, alpha, den, row_st, srcs, b2, nullptr, Ah, Ah,
        wes3, wed3, es, ed, E);

    // ---- Layer 3: aggregate-then-transform ----
    attn_alpha2<2><<<nblk4, 256, 0, stream>>>(es, ed, row_st, srcs, alpha, den, N, E);
    aggregate_x_dual<<<N, 512, 0, stream>>>(Ah, alpha, den, row_st, srcs, h_h, E);
    gemm_f16_ep<<<dim3(8, mblk), 256, 0, stream>>>(
        h_h, Bt3, (float*)d_out, b3, Ah, N, 512, 1024);
}